// Round 2
// baseline (136.873 us; speedup 1.0000x reference)
//
#include <hip/hip_runtime.h>

#define BLANK 36
#define NEG -1e30f
#define CC 37
#define LOG37 3.6109179126442243f

__device__ __forceinline__ float logaddexp_f(float a, float b) {
    float m = fmaxf(a, b);
    float d = fabsf(a - b);
    return m + __logf(1.0f + __expf(-d));
}

// DPP helpers (VALU pipe): 0x110|n = row_shr:n, 0x142 = row_bcast15,
// 0x143 = row_bcast31. bound_ctrl=true -> OOB lanes read 0.
#define DPP0(src, ctrl) __builtin_amdgcn_update_dpp(0, (src), (ctrl), 0xf, 0xf, true)
#define DPPM(old, src, ctrl) __builtin_amdgcn_update_dpp((old), (src), (ctrl), 0xf, 0xf, false)

// ============ FAST PATH v3: two samples/wave + fused finalization ==========
// R14: R13's pair-packed kernel is at its HBM floor (~12-14 us for 77.6 MB).
// Remaining slack was the reduce_mean dispatch + per_sample round-trip
// (~4-6 us). This version finalizes in-kernel: per block, wave0 lane0
// atomicAdd(double) of the pair's loss sum into ws[0], __threadfence,
// ticket via atomicAdd(ws+8); last ticket reads the final sum (atomic rmw
// returns old) and writes out[0] = sum/B. ws[0..15] zeroed by a 16-B
// hipMemsetAsync before launch (ws arrives poisoned). Deterministic to
// ~1e-13 (double accumulation, order-independent at tolerance).
__global__ __launch_bounds__(128, 2) void ctc_fused_ab2_kernel(
    const float* __restrict__ logits,        // [B, T, C]
    const int*   __restrict__ targets,       // [B * L]
    const int*   __restrict__ input_lengths, // [B]
    const int*   __restrict__ target_lengths,// [B]
    double*      __restrict__ accum,         // ws[0] (zeroed)
    int*         __restrict__ counter,       // ws[8] (zeroed)
    float*       __restrict__ out,           // [1]
    int B, int T, int L)
{
    __shared__ float lds[2 * 2368 + 72];
    const int lane = threadIdx.x & 63;
    const int wib  = threadIdx.x >> 6;       // 0 = alpha, 1 = beta
    const int h    = lane >> 5;              // sample within pair
    const int l    = lane & 31;              // per-sample lane
    const int b0   = blockIdx.x * 2;
    const int bme  = b0 + h;

    float* Xw   = lds + wib * 2368;          // this wave's chunk-pair buffer
    float* Xh   = Xw + h * 1184;             // this half's 32x37 rows
    float* exch = lds + 4736;                // combine exchange (2x35)

    const int halfT = T >> 1;
    const int NCh   = halfT >> 5;            // 32-row chunks per wave

    const int tl_lane  = target_lengths[bme];
    const int il_lane  = input_lengths[bme];
    const int end_lane = 2 * tl_lane;
    const int s_ilA = __builtin_amdgcn_readlane(il_lane, 0);
    const int s_ilB = __builtin_amdgcn_readlane(il_lane, 32);

    // ext for my state: alpha lane l = state l+1; beta lane l = state 31-l.
    // Odd state <=> even l. Clamp target index for L<16 memory safety (only
    // affects invalid states).
    int ext_w = BLANK;
    if (!(l & 1)) {
        int ti = (wib == 0) ? (l >> 1) : (15 - (l >> 1));
        if (ti >= L) ti = L - 1;
        if (ti < 0) ti = 0;
        ext_w = targets[bme * L + ti];
    }
    const int exo = __shfl_up(ext_w, 2);     // within-half for l>=2 (guarded)
    float kf;
    if (wib == 0)   // skip into state s=l+1 from s-2 (lane l-2)
        kf = (l >= 2 && ext_w != BLANK && ext_w != exo) ? 1.0f : 0.0f;
    else            // skip from state s=31-l to s+2 (lane l-2)
        kf = ((33 - l) <= 2 * L && exo != BLANK && exo != ext_w) ? 1.0f : 0.0f;

    const bool c16 = (l == 16);              // lanes 16, 48 (in-half row bnd)
    const bool c17 = (l == 17);              // lanes 17, 49
    const bool cz0 = (l == 0);               // lanes 0, 32 (zx injection)
    const int bcast_addr = (((lane & 32) | 31) << 2);   // half-bcast source

    const float4* baseH4 = (const float4*)(logits + (size_t)bme * T * CC);
    const float* pwp = Xh + ext_w;           // my-state prob column
    const float* pbp = Xh + 36;              // blank prob column (uniform/half)

    auto SHIFTS = [&](float x, float inj, float& a1, float& a2) {
        const int xi  = __float_as_int(x);
        const int s1  = DPP0(xi, 0x111);
        const int s2  = DPP0(xi, 0x112);
        const int b15 = DPP0(xi, 0x142);
        const int y15 = DPP0(s1, 0x142);
        a1 = cz0 ? inj : __int_as_float(c16 ? b15 : s1);
        a2 = __int_as_float(c16 ? y15 : (c17 ? b15 : s2));
    };

    auto RESCALE = [&](float& x, float& x2, float& racc) {
        float m = fmaxf(x, x2);
        m = fmaxf(m, __int_as_float(DPPM(__float_as_int(m), __float_as_int(m), 0x111)));
        m = fmaxf(m, __int_as_float(DPPM(__float_as_int(m), __float_as_int(m), 0x112)));
        m = fmaxf(m, __int_as_float(DPPM(__float_as_int(m), __float_as_int(m), 0x114)));
        m = fmaxf(m, __int_as_float(DPPM(__float_as_int(m), __float_as_int(m), 0x118)));
        m = fmaxf(m, __int_as_float(DPPM(__float_as_int(m), __float_as_int(m), 0x142)));
        // lane 31 holds max(0..31), lane 63 max(32..63); broadcast per half
        float gm = __int_as_float(__builtin_amdgcn_ds_bpermute(bcast_addr, __float_as_int(m)));
        gm = fmaxf(gm, 1e-30f);
        const float inv = __builtin_amdgcn_rcpf(gm);
        x *= inv; x2 *= inv;
        racc += __logf(gm);
    };

    auto SOFTMAX = [&](float* Xn) {          // 64 rows (2 samples x 32), x37
        float xr[CC];
        const float* row = Xn + lane * CC;
        #pragma unroll
        for (int c2 = 0; c2 < CC; ++c2) xr[c2] = row[c2];
        float m = xr[0];
        #pragma unroll
        for (int c2 = 1; c2 < CC; ++c2) m = fmaxf(m, xr[c2]);
        float ss = 0.0f;
        #pragma unroll
        for (int c2 = 0; c2 < CC; ++c2) { xr[c2] = __expf(xr[c2] - m); ss += xr[c2]; }
        const float inv = 37.0f / ss;
        float* wrow = Xn + lane * CC;
        #pragma unroll
        for (int c2 = 0; c2 < CC; ++c2) wrow[c2] = xr[c2] * inv;
    };

    auto STAGE = [&](int tbase) {            // global -> this half's rows
        const float4* s4 = baseH4 + ((tbase * CC) >> 2);
        float4* d4 = (float4*)Xh;
        #pragma unroll
        for (int k = 0; k < 9; ++k) d4[k * 32 + l] = s4[k * 32 + l];
        if (l < 8) d4[288 + l] = s4[288 + l];
        __builtin_amdgcn_s_waitcnt(0);
    };

    float z = 0.0f, zx = 0.0f, racc = 0.0f, capv = NEG;
    float pw[16], pb[16];

    if (wib == 0) {
        // =================== ALPHA: t = 0 .. halfT-1 =======================
        STAGE(0);
        SOFTMAX(Xw);
        __builtin_amdgcn_s_waitcnt(0);
        #pragma unroll 1
        for (int c = 0; c < NCh; ++c) {
            const bool more = (c + 1 < NCh);
            float4 f0 = {}, f1 = {}, f2 = {}, f3 = {}, f4 = {},
                   f5 = {}, f6 = {}, f7 = {}, f8 = {}, f9 = {};
            if (more) {
                const float4* s4 = baseH4 + ((((c + 1) << 5) * CC) >> 2);
                f0 = s4[l];       f1 = s4[32 + l];  f2 = s4[64 + l];
                f3 = s4[96 + l];  f4 = s4[128 + l]; f5 = s4[160 + l];
                f6 = s4[192 + l]; f7 = s4[224 + l]; f8 = s4[256 + l];
                if (l < 8) f9 = s4[288 + l];
            }
            #pragma unroll
            for (int j = 0; j < 16; ++j) { pw[j] = pwp[j * CC]; pb[j] = pbp[j * CC]; }
            #pragma unroll
            for (int r = 0; r < 32; ++r) {
                const float p   = pw[r & 15];
                const float pbv = pb[r & 15];
                if (r < 16) { pw[r & 15] = pwp[(r + 16) * CC]; pb[r & 15] = pbp[(r + 16) * CC]; }
                if (c == 0 && r == 0) {
                    z  = cz0 ? p : 0.0f;     // state 1
                    zx = pbv;                // state 0 (blank)
                } else {
                    float a1, a2;
                    SHIFTS(z, zx, a1, a2);   // inject state0 at lane 0/32
                    z = fmaf(kf, a2, z + a1) * p;
                    zx *= pbv;
                }
                const int tt = (c << 5) + r;
                if (s_ilA == tt + 1 || s_ilB == tt + 1) {
                    const float cv = __logf(fmaxf(z, 1e-35f)) + racc - (float)(tt + 1) * LOG37;
                    capv = (il_lane == tt + 1) ? cv : capv;
                }
                if ((r & 15) == 15) RESCALE(z, zx, racc);
            }
            if (more) {
                float4* d4 = (float4*)Xh;
                d4[l] = f0;       d4[32 + l] = f1;  d4[64 + l] = f2;
                d4[96 + l] = f3;  d4[128 + l] = f4; d4[160 + l] = f5;
                d4[192 + l] = f6; d4[224 + l] = f7; d4[256 + l] = f8;
                if (l < 8) d4[288 + l] = f9;
                __builtin_amdgcn_s_waitcnt(0);
                SOFTMAX(Xw);
                __builtin_amdgcn_s_waitcnt(0);
            }
        }
    } else {
        // =================== BETA: t = T-1 .. halfT (states reversed) ======
        // lane l = state 31-l; zx = state 32 (tail blank): zx *= p_blank,
        // injects u[32] into lane 0/32's a1. Invalid states (> end) stay
        // exactly 0 (fed only from higher invalid states).
        STAGE(T - 32);
        SOFTMAX(Xw);
        __builtin_amdgcn_s_waitcnt(0);
        #pragma unroll 1
        for (int i = 0; i < NCh; ++i) {
            const bool more = (i + 1 < NCh);
            float4 f0 = {}, f1 = {}, f2 = {}, f3 = {}, f4 = {},
                   f5 = {}, f6 = {}, f7 = {}, f8 = {}, f9 = {};
            if (more) {
                const float4* s4 = baseH4 + (((T - (i + 2) * 32) * CC) >> 2);
                f0 = s4[l];       f1 = s4[32 + l];  f2 = s4[64 + l];
                f3 = s4[96 + l];  f4 = s4[128 + l]; f5 = s4[160 + l];
                f6 = s4[192 + l]; f7 = s4[224 + l]; f8 = s4[256 + l];
                if (l < 8) f9 = s4[288 + l];
            }
            const int tbase = T - (i + 1) * 32;
            #pragma unroll
            for (int j = 0; j < 16; ++j) { pw[j] = pwp[(31 - j) * CC]; pb[j] = pbp[(31 - j) * CC]; }
            #pragma unroll
            for (int r = 0; r < 32; ++r) {
                const int tt = tbase + 31 - r;
                if (s_ilA == tt + 1 || s_ilB == tt + 1) {   // re-init at t=il-1
                    const bool cond = (il_lane == tt + 1);
                    const float zi = (l == 31 - end_lane || l == 32 - end_lane) ? 1.0f : 0.0f;
                    z    = cond ? zi : z;
                    zx   = cond ? ((end_lane == 32) ? 1.0f : 0.0f) : zx;
                    racc = cond ? 0.0f : racc;
                }
                const float p   = pw[r & 15];
                const float pbv = pb[r & 15];
                if (r < 16) { pw[r & 15] = pwp[(15 - r) * CC]; pb[r & 15] = pbp[(15 - r) * CC]; }
                const float u  = z * p;
                const float uE = zx * pbv;
                float a1, a2;
                SHIFTS(u, uE, a1, a2);
                z  = fmaf(kf, a2, u + a1);
                zx = uE;
                if ((r & 15) == 15) RESCALE(z, zx, racc);
            }
            if (more) {
                float4* d4 = (float4*)Xh;
                d4[l] = f0;       d4[32 + l] = f1;  d4[64 + l] = f2;
                d4[96 + l] = f3;  d4[128 + l] = f4; d4[160 + l] = f5;
                d4[192 + l] = f6; d4[224 + l] = f7; d4[256 + l] = f8;
                if (l < 8) d4[288 + l] = f9;
                __builtin_amdgcn_s_waitcnt(0);
                SOFTMAX(Xw);
                __builtin_amdgcn_s_waitcnt(0);
            }
        }
    }

    // =================== combine + in-kernel finalization ==================
    __syncthreads();
    if (wib == 1) {
        exch[h * 35 + (31 - l)] = z;         // states 31..0
        if (l == 0) { exch[h * 35 + 32] = zx; exch[h * 35 + 33] = racc; }
    }
    __syncthreads();
    if (wib == 0) {
        const float bs = exch[h * 35 + l + 1];            // beta at my state
        float prod = z * bs + (cz0 ? zx * exch[h * 35] : 0.0f);
        #pragma unroll
        for (int o = 16; o > 0; o >>= 1) prod += __shfl_xor(prod, o);  // per-half
        const float rb = exch[h * 35 + 33];
        int i1 = (lane & 32) + end_lane - 1;
        if (i1 < 0) i1 = 0;
        int i2 = i1 - 1;
        if (i2 < 0) i2 = 0;
        const float e1 = __shfl(capv, i1);
        const float e2 = __shfl(capv, i2);
        const float fcap = logaddexp_f(e1, e2);
        const float fmid = __logf(fmaxf(prod, 1e-37f)) + racc + rb
                           - (float)il_lane * LOG37;
        const float final_v = (il_lane <= halfT) ? fcap : fmid;
        const float myloss = cz0 ? (-final_v / (float)tl_lane) : 0.0f; // lanes 0,32
        const float otherloss = __shfl(myloss, 32);
        if (lane == 0) {
            atomicAdd(accum, (double)(myloss + otherloss));
            __threadfence();
            const int tkt = atomicAdd(counter, 1);
            if (tkt == (int)gridDim.x - 1) {          // last block finalizes
                __threadfence();
                const double s = atomicAdd(accum, 0.0);   // rmw returns final
                out[0] = (float)(s / (double)B);
            }
        }
    }
}

// ============ FAST PATH v1 (proven, one sample/block; for 16<L<=31) ========
__global__ __launch_bounds__(128, 4) void ctc_fused_ab_kernel(
    const float* __restrict__ logits,        // [B, T, C]
    const int*   __restrict__ targets,       // [B * L]
    const int*   __restrict__ input_lengths, // [B]
    const int*   __restrict__ target_lengths,// [B]
    float*       __restrict__ per_sample,    // [B]
    int B, int T, int L)
{
    __shared__ float lds[2 * 2368 + 66];
    const int lane = threadIdx.x & 63;
    const int wib  = threadIdx.x >> 6;       // 0 = alpha, 1 = beta
    const int b    = blockIdx.x;

    float* Xw   = lds + wib * 2368;          // this wave's chunk buffer
    float* exch = lds + 4736;                // combine exchange (65 floats)

    const int S = 2 * L + 1;
    const int tlen_s = __builtin_amdgcn_readfirstlane(target_lengths[b]);
    const int ilen_s = __builtin_amdgcn_readfirstlane(input_lengths[b]);
    const int end_s  = 2 * tlen_s;
    const int halfT  = T >> 1;
    const int NC     = T >> 6;               // 64-row chunks (NC even)
    const int NCh    = NC >> 1;              // chunks per wave

    // per-wave state<->lane mapping: alpha natural, beta reversed
    const int st = (wib == 0) ? lane : (63 - lane);
    int ext_w = BLANK;
    if (st < S && (st & 1)) ext_w = targets[b * L + (st >> 1)];
    const int exo = __shfl_up(ext_w, 2);     // alpha: ext[st-2]; beta: ext[st+2]
    float kf;
    if (wib == 0)
        kf = ((st >= 2) && (st < S) && (ext_w != BLANK) && (ext_w != exo)) ? 1.0f : 0.0f;
    else
        kf = ((st + 2 < S) && (exo != BLANK) && (exo != ext_w)) ? 1.0f : 0.0f;

    // row-boundary lanes for the DPP shift patches (verified R10-R12)
    const bool c16 = ((lane & 31) == 16);
    const bool c17 = ((lane & 31) == 17);
    const bool c32 = (lane == 32);
    const bool c33 = (lane == 33);

    const float4* src = (const float4*)(logits + (size_t)b * T * CC);

    // shifted neighbors (x[l-1], x[l-2]) with row-boundary patches
    auto SHIFTS = [&](float x, float& a1, float& a2) {
        const int xi  = __float_as_int(x);
        const int s1  = DPP0(xi, 0x111);
        const int s2  = DPP0(xi, 0x112);
        const int b15 = DPP0(xi, 0x142);
        const int b31 = DPP0(xi, 0x143);
        const int y15 = DPP0(s1, 0x142);
        const int y31 = DPP0(s1, 0x143);
        a1 = __int_as_float(c16 ? b15 : (c32 ? b31 : s1));
        a2 = __int_as_float(c16 ? y15 : (c17 ? b15 : (c32 ? y31 : (c33 ? b31 : s2))));
    };

    auto RESCALE = [&](float& x, float& racc) {  // DPP reduce + readlane
        float m = x;
        m = fmaxf(m, __int_as_float(DPPM(__float_as_int(m), __float_as_int(m), 0x111)));
        m = fmaxf(m, __int_as_float(DPPM(__float_as_int(m), __float_as_int(m), 0x112)));
        m = fmaxf(m, __int_as_float(DPPM(__float_as_int(m), __float_as_int(m), 0x114)));
        m = fmaxf(m, __int_as_float(DPPM(__float_as_int(m), __float_as_int(m), 0x118)));
        m = fmaxf(m, __int_as_float(DPPM(__float_as_int(m), __float_as_int(m), 0x142)));
        m = fmaxf(m, __int_as_float(DPPM(__float_as_int(m), __float_as_int(m), 0x143)));
        float gm = __int_as_float(__builtin_amdgcn_readlane(__float_as_int(m), 63));
        gm = fmaxf(gm, 1e-30f);
        x *= (1.0f / gm);
        racc += __logf(gm);
    };

    auto SOFTMAX = [&](float* Xn) {          // in-place row softmax scaled by 37
        float xr[CC];
        const float* row = Xn + lane * CC;
        #pragma unroll
        for (int c2 = 0; c2 < CC; ++c2) xr[c2] = row[c2];
        float m = xr[0];
        #pragma unroll
        for (int c2 = 1; c2 < CC; ++c2) m = fmaxf(m, xr[c2]);
        float ss = 0.0f;
        #pragma unroll
        for (int c2 = 0; c2 < CC; ++c2) { xr[c2] = __expf(xr[c2] - m); ss += xr[c2]; }
        const float inv = 37.0f / ss;
        float* wrow = Xn + lane * CC;
        #pragma unroll
        for (int c2 = 0; c2 < CC; ++c2) wrow[c2] = xr[c2] * inv;
    };

    auto STAGE = [&](const float4* s2g) {    // global -> this wave's buffer
        float4* dst = (float4*)Xw;
        #pragma unroll
        for (int k = 0; k < 9; ++k) dst[k * 64 + lane] = s2g[k * 64 + lane];
        if (lane < 16) dst[576 + lane] = s2g[576 + lane];
        __builtin_amdgcn_s_waitcnt(0);
    };

    float z = 0.0f, racc = 0.0f, capv = NEG; // z: alpha (w0) / beta (w1)
    float pw[16];

    if (wib == 0) {
        // =================== ALPHA: t = 0 .. halfT-1 =======================
        STAGE(src);
        SOFTMAX(Xw);
        __builtin_amdgcn_s_waitcnt(0);
        #pragma unroll 1
        for (int c = 0; c < NCh; ++c) {
            const bool more = (c + 1 < NCh);
            float4 f0 = {}, f1 = {}, f2 = {}, f3 = {}, f4 = {},
                   f5 = {}, f6 = {}, f7 = {}, f8 = {}, f9 = {};
            if (more) {
                const float4* s2g = src + (size_t)(c + 1) * 592;
                f0 = s2g[lane];       f1 = s2g[64 + lane];  f2 = s2g[128 + lane];
                f3 = s2g[192 + lane]; f4 = s2g[256 + lane]; f5 = s2g[320 + lane];
                f6 = s2g[384 + lane]; f7 = s2g[448 + lane]; f8 = s2g[512 + lane];
                if (lane < 16) f9 = s2g[576 + lane];
            }
            const int tbase = c << 6;
            #pragma unroll
            for (int j = 0; j < 16; ++j) pw[j] = Xw[j * CC + ext_w];
            #pragma unroll
            for (int r = 0; r < 64; ++r) {
                const float p = pw[r & 15];
                if (r + 16 < 64) pw[r & 15] = Xw[(r + 16) * CC + ext_w];
                if (c == 0 && r == 0) {
                    z = (lane <= 1) ? p : 0.0f;
                    if (ilen_s == 1) capv = __logf(fmaxf(z, 1e-35f)) - LOG37;
                } else {
                    float a1, a2;
                    SHIFTS(z, a1, a2);
                    z = fmaf(kf, a2, z + a1) * p;
                    const int tt = tbase + r;
                    if (ilen_s == tt + 1)
                        capv = __logf(fmaxf(z, 1e-35f)) + racc - (float)(tt + 1) * LOG37;
                }
                if ((r & 15) == 15) RESCALE(z, racc);
            }
            if (more) {
                float4* dst = (float4*)Xw;
                dst[lane] = f0;       dst[64 + lane] = f1;  dst[128 + lane] = f2;
                dst[192 + lane] = f3; dst[256 + lane] = f4; dst[320 + lane] = f5;
                dst[384 + lane] = f6; dst[448 + lane] = f7; dst[512 + lane] = f8;
                if (lane < 16) dst[576 + lane] = f9;
                __builtin_amdgcn_s_waitcnt(0);
                SOFTMAX(Xw);
                __builtin_amdgcn_s_waitcnt(0);
            }
        }
    } else {
        // =================== BETA: t = T-1 .. halfT (reversed states) ======
        STAGE(src + (size_t)(NC - 1) * 592);
        SOFTMAX(Xw);
        __builtin_amdgcn_s_waitcnt(0);
        const int il1 = ilen_s - 1;
        #pragma unroll 1
        for (int i = 0; i < NCh; ++i) {
            const bool more = (i + 1 < NCh);
            float4 f0 = {}, f1 = {}, f2 = {}, f3 = {}, f4 = {},
                   f5 = {}, f6 = {}, f7 = {}, f8 = {}, f9 = {};
            if (more) {
                const float4* s2g = src + (size_t)(NC - 2 - i) * 592;
                f0 = s2g[lane];       f1 = s2g[64 + lane];  f2 = s2g[128 + lane];
                f3 = s2g[192 + lane]; f4 = s2g[256 + lane]; f5 = s2g[320 + lane];
                f6 = s2g[384 + lane]; f7 = s2g[448 + lane]; f8 = s2g[512 + lane];
                if (lane < 16) f9 = s2g[576 + lane];
            }
            const int cbase = (NC - 1 - i) << 6;
            #pragma unroll
            for (int j = 0; j < 16; ++j) pw[j] = Xw[(63 - j) * CC + ext_w];
            #pragma unroll
            for (int r = 0; r < 64; ++r) {
                const int tt = cbase + 63 - r;
                if (tt == il1) {                 // wave-uniform re-init
                    z = (lane == 63 - end_s || lane == 64 - end_s) ? 1.0f : 0.0f;
                    racc = 0.0f;
                }
                const float p = pw[r & 15];
                if (r + 16 < 64) pw[r & 15] = Xw[(63 - (r + 16)) * CC + ext_w];
                const float u = z * p;
                float a1, a2;
                SHIFTS(u, a1, a2);
                z = fmaf(kf, a2, u + a1);
                if ((r & 15) == 15) RESCALE(z, racc);
            }
            if (more) {
                float4* dst = (float4*)Xw;
                dst[lane] = f0;       dst[64 + lane] = f1;  dst[128 + lane] = f2;
                dst[192 + lane] = f3; dst[256 + lane] = f4; dst[320 + lane] = f5;
                dst[384 + lane] = f6; dst[448 + lane] = f7; dst[512 + lane] = f8;
                if (lane < 16) dst[576 + lane] = f9;
                __builtin_amdgcn_s_waitcnt(0);
                SOFTMAX(Xw);
                __builtin_amdgcn_s_waitcnt(0);
            }
        }
    }

    // =================== combine ==========================================
    __syncthreads();
    if (wib == 1) {
        exch[63 - lane] = z;                 // exch[state] = beta_tm[state]
        if (lane == 0) exch[64] = racc;
    }
    __syncthreads();
    if (wib == 0) {
        const float bs = exch[lane];         // beta at my state (0 if invalid)
        const float rb = exch[64];
        float prod = z * bs;                 // garbage alpha lanes x 0 = 0
        #pragma unroll
        for (int o = 32; o > 0; o >>= 1) prod += __shfl_xor(prod, o);
        float final_v;
        if (ilen_s <= halfT) {               // alpha capture path
            const float e1 = __shfl(capv, end_s);
            const float e2 = __shfl(capv, end_s - 1);
            final_v = logaddexp_f(e1, e2);
        } else {                             // midpoint product path
            final_v = __logf(fmaxf(prod, 1e-37f)) + racc + rb - (float)ilen_s * LOG37;
        }
        if (lane == 0) per_sample[b] = -final_v / (float)tlen_s;
    }
}

// ============ FALLBACK PATH (proven R2 kernels) ============================
__global__ __launch_bounds__(256) void lse_kernel(
    const float* __restrict__ logits, float* __restrict__ denom, int N)
{
    __shared__ float lds[256 * CC];
    const int lane = threadIdx.x & 63;
    const int wib  = threadIdx.x >> 6;
    const int wave = blockIdx.x * 4 + wib;
    const long long row0 = (long long)wave * 64;
    if (row0 >= N) return;
    const int wbase = wib * 64 * CC;
    const float4* src4 = (const float4*)(logits + row0 * CC);
    const long long n4_remaining = ((long long)N * CC - row0 * CC) / 4;
    float4* lds4 = (float4*)(lds + wbase);
    #pragma unroll
    for (int k = 0; k < 10; ++k) {
        const int idx = k * 64 + lane;
        if (idx < 592 && idx < n4_remaining) lds4[idx] = src4[idx];
    }
    __builtin_amdgcn_s_waitcnt(0);
    const long long row = row0 + lane;
    if (row >= N) return;
    const float* x = lds + wbase + lane * CC;
    float m = x[0];
    #pragma unroll
    for (int c = 1; c < CC; ++c) m = fmaxf(m, x[c]);
    float s = 0.0f;
    #pragma unroll
    for (int c = 0; c < CC; ++c) s += __expf(x[c] - m);
    denom[row] = m + __logf(s);
}

__global__ __launch_bounds__(256) void ctc_alpha2_kernel(
    const float* __restrict__ logits, const float* __restrict__ denom,
    const int* __restrict__ targets, const int* __restrict__ input_lengths,
    const int* __restrict__ target_lengths, float* __restrict__ per_sample,
    int B, int T, int L)
{
    const int wave = (int)((blockIdx.x * blockDim.x + threadIdx.x) >> 6);
    const int lane = threadIdx.x & 63;
    if (wave >= B) return;
    const int b = wave;
    const int S = 2 * L + 1;
    const int tlen = target_lengths[b];
    const int ilen = input_lengths[b];
    const int end_idx = 2 * tlen;
    int ext_s = BLANK;
    if (lane < S && (lane & 1)) ext_s = targets[b * L + (lane >> 1)];
    const int ext_sm2 = __shfl_up(ext_s, 2);
    const bool skip_ok = (lane < S) && (lane >= 2) && (ext_s != BLANK) && (ext_s != ext_sm2);
    const bool valid = lane < (2 * tlen + 1);
    const float* lg = logits + (size_t)b * T * CC;
    const float* dn = denom + (size_t)b * T;
    float x_cur = lg[ext_s];
    float d_cur = dn[0];
    float x_nx = (T > 1) ? lg[CC + ext_s] : 0.0f;
    float d_nx = (T > 1) ? dn[1] : 0.0f;
    float final_v = NEG;
    float alpha = (valid && lane <= 1) ? (x_cur - d_cur) : NEG;
    if (ilen == 1) {
        const float e1 = __shfl(alpha, end_idx);
        const float e2 = __shfl(alpha, end_idx - 1);
        final_v = logaddexp_f(e1, e2);
    }
    for (int tt = 1; tt < T; ++tt) {
        x_cur = x_nx; d_cur = d_nx;
        if (tt + 1 < T) {
            x_nx = lg[(size_t)(tt + 1) * CC + ext_s];
            d_nx = dn[tt + 1];
        }
        const float lpe = x_cur - d_cur;
        float a1 = __shfl_up(alpha, 1);
        if (lane == 0) a1 = NEG;
        float a2 = __shfl_up(alpha, 2);
        if (!skip_ok) a2 = NEG;
        const float m = fmaxf(fmaxf(alpha, a1), a2);
        const float s = __expf(alpha - m) + __expf(a1 - m) + __expf(a2 - m);
        const float na = m + __logf(s) + lpe;
        alpha = valid ? na : NEG;
        if (ilen == tt + 1) {
            const float e1 = __shfl(alpha, end_idx);
            const float e2 = __shfl(alpha, end_idx - 1);
            final_v = logaddexp_f(e1, e2);
        }
    }
    if (lane == 0) per_sample[b] = -final_v / (float)tlen;
}

__global__ __launch_bounds__(256) void ctc_alpha_mono_kernel(
    const float* __restrict__ logits, const int* __restrict__ targets,
    const int* __restrict__ input_lengths, const int* __restrict__ target_lengths,
    float* __restrict__ per_sample, int B, int T, int L)
{
    const int wave = (int)((blockIdx.x * blockDim.x + threadIdx.x) >> 6);
    const int lane = threadIdx.x & 63;
    if (wave >= B) return;
    const int b = wave;
    const int S = 2 * L + 1;
    const int tlen = target_lengths[b];
    const int ilen = input_lengths[b];
    const int end_idx = 2 * tlen;
    int ext_s = BLANK;
    if (lane < S && (lane & 1)) ext_s = targets[b * L + (lane >> 1)];
    const int ext_sm2 = __shfl_up(ext_s, 2);
    const bool skip_ok = (lane < S) && (lane >= 2) && (ext_s != BLANK) && (ext_s != ext_sm2);
    const bool valid = lane < (2 * tlen + 1);
    const float* lg = logits + (size_t)b * T * CC;
    float alpha = NEG, final_v = NEG;
    for (int t = 0; t < T; ++t) {
        float x = (lane < CC) ? lg[t * CC + lane] : -3.0e38f;
        float mx = x;
        #pragma unroll
        for (int o = 32; o > 0; o >>= 1) mx = fmaxf(mx, __shfl_xor(mx, o));
        float e = (lane < CC) ? __expf(x - mx) : 0.0f;
        float se = e;
        #pragma unroll
        for (int o = 32; o > 0; o >>= 1) se += __shfl_xor(se, o);
        const float lp = x - mx - __logf(se);
        const float lpe = __shfl(lp, ext_s);
        float newa;
        if (t == 0) {
            newa = (lane <= 1) ? lpe : NEG;
        } else {
            float a1 = __shfl_up(alpha, 1);
            if (lane == 0) a1 = NEG;
            float a2 = __shfl_up(alpha, 2);
            if (!skip_ok) a2 = NEG;
            newa = logaddexp_f(logaddexp_f(alpha, a1), a2) + lpe;
        }
        if (!valid) newa = NEG;
        alpha = newa;
        if (ilen == t + 1) {
            const float e1 = __shfl(alpha, end_idx);
            const float e2 = __shfl(alpha, end_idx - 1);
            final_v = logaddexp_f(e1, e2);
        }
    }
    if (lane == 0) per_sample[b] = -final_v / (float)tlen;
}

// ---------------- Deterministic mean over B samples (fallback paths) -------
__global__ __launch_bounds__(256) void reduce_mean_kernel(
    const float* __restrict__ ps, float* __restrict__ out, int B)
{
    float s = 0.0f;
    for (int i = threadIdx.x; i < B; i += 256) s += ps[i];
    #pragma unroll
    for (int o = 32; o > 0; o >>= 1) s += __shfl_xor(s, o);
    __shared__ float sm[4];
    const int w = threadIdx.x >> 6, l = threadIdx.x & 63;
    if (l == 0) sm[w] = s;
    __syncthreads();
    if (threadIdx.x == 0) {
        out[0] = (sm[0] + sm[1] + sm[2] + sm[3]) / (float)B;
    }
}

extern "C" void kernel_launch(void* const* d_in, const int* in_sizes, int n_in,
                              void* d_out, int out_size, void* d_ws, size_t ws_size,
                              hipStream_t stream) {
    const float* logits         = (const float*)d_in[0];
    const int*   targets        = (const int*)d_in[1];
    const int*   input_lengths  = (const int*)d_in[2];
    const int*   target_lengths = (const int*)d_in[3];

    const int B = in_sizes[2];
    const int L = in_sizes[1] / B;
    const int T = in_sizes[0] / (B * CC);
    const long long N = (long long)B * T;

    float* per_sample = (float*)d_ws;
    float* scratch    = per_sample + B;
    float* out        = (float*)d_out;

    const size_t ws_mid = ((size_t)B + (size_t)N) * sizeof(float);
    const int nblocks_alpha = (B * 64 + 255) / 256;
    const long long nwaves = (N + 63) / 64;

    const bool fast2 = (B % 2 == 0) && (T % 64 == 0) && T >= 64 && L <= 16 &&
                       ws_size >= 16;
    const bool fast1 = (T % 128 == 0) && T >= 128 && L <= 31 &&
                       ws_size >= (size_t)B * sizeof(float);

    if (fast2) {
        // ws[0..7]: double accum, ws[8..11]: int ticket counter
        hipMemsetAsync(d_ws, 0, 16, stream);
        ctc_fused_ab2_kernel<<<B / 2, 128, 0, stream>>>(
            logits, targets, input_lengths, target_lengths,
            (double*)d_ws, (int*)((char*)d_ws + 8), out, B, T, L);
    } else if (fast1) {
        ctc_fused_ab_kernel<<<B, 128, 0, stream>>>(
            logits, targets, input_lengths, target_lengths, per_sample, B, T, L);
        reduce_mean_kernel<<<1, 256, 0, stream>>>(per_sample, out, B);
    } else if (ws_size >= ws_mid && T >= 2) {
        lse_kernel<<<(int)((nwaves + 3) / 4), 256, 0, stream>>>(logits, scratch, (int)N);
        ctc_alpha2_kernel<<<nblocks_alpha, 256, 0, stream>>>(
            logits, scratch, targets, input_lengths, target_lengths, per_sample, B, T, L);
        reduce_mean_kernel<<<1, 256, 0, stream>>>(per_sample, out, B);
    } else {
        ctc_alpha_mono_kernel<<<nblocks_alpha, 256, 0, stream>>>(
            logits, targets, input_lengths, target_lengths, per_sample, B, T, L);
        reduce_mean_kernel<<<1, 256, 0, stream>>>(per_sample, out, B);
    }
}

// Round 3
// 133.973 us; speedup vs baseline: 1.0216x; 1.0216x over previous
//
#include <hip/hip_runtime.h>

#define BLANK 36
#define NEG -1e30f
#define CC 37
#define LOG37 3.6109179126442243f

__device__ __forceinline__ float logaddexp_f(float a, float b) {
    float m = fmaxf(a, b);
    float d = fabsf(a - b);
    return m + __logf(1.0f + __expf(-d));
}

// DPP helpers (VALU pipe): 0x110|n = row_shr:n, 0x142 = row_bcast15,
// 0x143 = row_bcast31. bound_ctrl=true -> OOB lanes read 0.
#define DPP0(src, ctrl) __builtin_amdgcn_update_dpp(0, (src), (ctrl), 0xf, 0xf, true)
#define DPPM(old, src, ctrl) __builtin_amdgcn_update_dpp((old), (src), (ctrl), 0xf, 0xf, false)

// ============ FAST PATH v4: two samples/wave + HIERARCHICAL finalization ===
// R15: R14's single-accumulator finalize serialized 2048 same-address atomic
// RMWs at the device coherence point (~20-30 us tail; kernel 75 us profiled,
// VALUBusy 13%). Fix per Guideline 12: two-level reduction.
//   ws layout (zeroed by 1 KiB hipMemsetAsync):
//     ws_d[0..63]  : per-bucket double partial sums (bucket = blockIdx % NB)
//     ws_d[64]     : global double sum
//     ((int*)(ws_d+65))[0..63] : per-bucket tickets
//     ((int*)(ws_d+65))[64]    : global bucket-done counter
// Worst same-address chain: ~16 (slot) + 16 (ticket) + 64 + 64 ~ 1-2 us,
// slot traffic parallel across 64 addresses. No spins -> no deadlock.
__global__ __launch_bounds__(128, 2) void ctc_fused_ab2_kernel(
    const float* __restrict__ logits,        // [B, T, C]
    const int*   __restrict__ targets,       // [B * L]
    const int*   __restrict__ input_lengths, // [B]
    const int*   __restrict__ target_lengths,// [B]
    double*      __restrict__ ws_d,          // workspace (zeroed first 1 KiB)
    float*       __restrict__ out,           // [1]
    int B, int T, int L)
{
    __shared__ float lds[2 * 2368 + 72];
    const int lane = threadIdx.x & 63;
    const int wib  = threadIdx.x >> 6;       // 0 = alpha, 1 = beta
    const int h    = lane >> 5;              // sample within pair
    const int l    = lane & 31;              // per-sample lane
    const int b0   = blockIdx.x * 2;
    const int bme  = b0 + h;

    float* Xw   = lds + wib * 2368;          // this wave's chunk-pair buffer
    float* Xh   = Xw + h * 1184;             // this half's 32x37 rows
    float* exch = lds + 4736;                // combine exchange (2x35)

    const int halfT = T >> 1;
    const int NCh   = halfT >> 5;            // 32-row chunks per wave

    const int tl_lane  = target_lengths[bme];
    const int il_lane  = input_lengths[bme];
    const int end_lane = 2 * tl_lane;
    const int s_ilA = __builtin_amdgcn_readlane(il_lane, 0);
    const int s_ilB = __builtin_amdgcn_readlane(il_lane, 32);

    // ext for my state: alpha lane l = state l+1; beta lane l = state 31-l.
    // Odd state <=> even l. Clamp target index for L<16 memory safety (only
    // affects invalid states).
    int ext_w = BLANK;
    if (!(l & 1)) {
        int ti = (wib == 0) ? (l >> 1) : (15 - (l >> 1));
        if (ti >= L) ti = L - 1;
        if (ti < 0) ti = 0;
        ext_w = targets[bme * L + ti];
    }
    const int exo = __shfl_up(ext_w, 2);     // within-half for l>=2 (guarded)
    float kf;
    if (wib == 0)   // skip into state s=l+1 from s-2 (lane l-2)
        kf = (l >= 2 && ext_w != BLANK && ext_w != exo) ? 1.0f : 0.0f;
    else            // skip from state s=31-l to s+2 (lane l-2)
        kf = ((33 - l) <= 2 * L && exo != BLANK && exo != ext_w) ? 1.0f : 0.0f;

    const bool c16 = (l == 16);              // lanes 16, 48 (in-half row bnd)
    const bool c17 = (l == 17);              // lanes 17, 49
    const bool cz0 = (l == 0);               // lanes 0, 32 (zx injection)
    const int bcast_addr = (((lane & 32) | 31) << 2);   // half-bcast source

    const float4* baseH4 = (const float4*)(logits + (size_t)bme * T * CC);
    const float* pwp = Xh + ext_w;           // my-state prob column
    const float* pbp = Xh + 36;              // blank prob column (uniform/half)

    auto SHIFTS = [&](float x, float inj, float& a1, float& a2) {
        const int xi  = __float_as_int(x);
        const int s1  = DPP0(xi, 0x111);
        const int s2  = DPP0(xi, 0x112);
        const int b15 = DPP0(xi, 0x142);
        const int y15 = DPP0(s1, 0x142);
        a1 = cz0 ? inj : __int_as_float(c16 ? b15 : s1);
        a2 = __int_as_float(c16 ? y15 : (c17 ? b15 : s2));
    };

    auto RESCALE = [&](float& x, float& x2, float& racc) {
        float m = fmaxf(x, x2);
        m = fmaxf(m, __int_as_float(DPPM(__float_as_int(m), __float_as_int(m), 0x111)));
        m = fmaxf(m, __int_as_float(DPPM(__float_as_int(m), __float_as_int(m), 0x112)));
        m = fmaxf(m, __int_as_float(DPPM(__float_as_int(m), __float_as_int(m), 0x114)));
        m = fmaxf(m, __int_as_float(DPPM(__float_as_int(m), __float_as_int(m), 0x118)));
        m = fmaxf(m, __int_as_float(DPPM(__float_as_int(m), __float_as_int(m), 0x142)));
        // lane 31 holds max(0..31), lane 63 max(32..63); broadcast per half
        float gm = __int_as_float(__builtin_amdgcn_ds_bpermute(bcast_addr, __float_as_int(m)));
        gm = fmaxf(gm, 1e-30f);
        const float inv = __builtin_amdgcn_rcpf(gm);
        x *= inv; x2 *= inv;
        racc += __logf(gm);
    };

    auto SOFTMAX = [&](float* Xn) {          // 64 rows (2 samples x 32), x37
        float xr[CC];
        const float* row = Xn + lane * CC;
        #pragma unroll
        for (int c2 = 0; c2 < CC; ++c2) xr[c2] = row[c2];
        float m = xr[0];
        #pragma unroll
        for (int c2 = 1; c2 < CC; ++c2) m = fmaxf(m, xr[c2]);
        float ss = 0.0f;
        #pragma unroll
        for (int c2 = 0; c2 < CC; ++c2) { xr[c2] = __expf(xr[c2] - m); ss += xr[c2]; }
        const float inv = 37.0f / ss;
        float* wrow = Xn + lane * CC;
        #pragma unroll
        for (int c2 = 0; c2 < CC; ++c2) wrow[c2] = xr[c2] * inv;
    };

    auto STAGE = [&](int tbase) {            // global -> this half's rows
        const float4* s4 = baseH4 + ((tbase * CC) >> 2);
        float4* d4 = (float4*)Xh;
        #pragma unroll
        for (int k = 0; k < 9; ++k) d4[k * 32 + l] = s4[k * 32 + l];
        if (l < 8) d4[288 + l] = s4[288 + l];
        __builtin_amdgcn_s_waitcnt(0);
    };

    float z = 0.0f, zx = 0.0f, racc = 0.0f, capv = NEG;
    float pw[16], pb[16];

    if (wib == 0) {
        // =================== ALPHA: t = 0 .. halfT-1 =======================
        STAGE(0);
        SOFTMAX(Xw);
        __builtin_amdgcn_s_waitcnt(0);
        #pragma unroll 1
        for (int c = 0; c < NCh; ++c) {
            const bool more = (c + 1 < NCh);
            float4 f0 = {}, f1 = {}, f2 = {}, f3 = {}, f4 = {},
                   f5 = {}, f6 = {}, f7 = {}, f8 = {}, f9 = {};
            if (more) {
                const float4* s4 = baseH4 + ((((c + 1) << 5) * CC) >> 2);
                f0 = s4[l];       f1 = s4[32 + l];  f2 = s4[64 + l];
                f3 = s4[96 + l];  f4 = s4[128 + l]; f5 = s4[160 + l];
                f6 = s4[192 + l]; f7 = s4[224 + l]; f8 = s4[256 + l];
                if (l < 8) f9 = s4[288 + l];
            }
            #pragma unroll
            for (int j = 0; j < 16; ++j) { pw[j] = pwp[j * CC]; pb[j] = pbp[j * CC]; }
            #pragma unroll
            for (int r = 0; r < 32; ++r) {
                const float p   = pw[r & 15];
                const float pbv = pb[r & 15];
                if (r < 16) { pw[r & 15] = pwp[(r + 16) * CC]; pb[r & 15] = pbp[(r + 16) * CC]; }
                if (c == 0 && r == 0) {
                    z  = cz0 ? p : 0.0f;     // state 1
                    zx = pbv;                // state 0 (blank)
                } else {
                    float a1, a2;
                    SHIFTS(z, zx, a1, a2);   // inject state0 at lane 0/32
                    z = fmaf(kf, a2, z + a1) * p;
                    zx *= pbv;
                }
                const int tt = (c << 5) + r;
                if (s_ilA == tt + 1 || s_ilB == tt + 1) {
                    const float cv = __logf(fmaxf(z, 1e-35f)) + racc - (float)(tt + 1) * LOG37;
                    capv = (il_lane == tt + 1) ? cv : capv;
                }
                if ((r & 15) == 15) RESCALE(z, zx, racc);
            }
            if (more) {
                float4* d4 = (float4*)Xh;
                d4[l] = f0;       d4[32 + l] = f1;  d4[64 + l] = f2;
                d4[96 + l] = f3;  d4[128 + l] = f4; d4[160 + l] = f5;
                d4[192 + l] = f6; d4[224 + l] = f7; d4[256 + l] = f8;
                if (l < 8) d4[288 + l] = f9;
                __builtin_amdgcn_s_waitcnt(0);
                SOFTMAX(Xw);
                __builtin_amdgcn_s_waitcnt(0);
            }
        }
    } else {
        // =================== BETA: t = T-1 .. halfT (states reversed) ======
        // lane l = state 31-l; zx = state 32 (tail blank): zx *= p_blank,
        // injects u[32] into lane 0/32's a1. Invalid states (> end) stay
        // exactly 0 (fed only from higher invalid states).
        STAGE(T - 32);
        SOFTMAX(Xw);
        __builtin_amdgcn_s_waitcnt(0);
        #pragma unroll 1
        for (int i = 0; i < NCh; ++i) {
            const bool more = (i + 1 < NCh);
            float4 f0 = {}, f1 = {}, f2 = {}, f3 = {}, f4 = {},
                   f5 = {}, f6 = {}, f7 = {}, f8 = {}, f9 = {};
            if (more) {
                const float4* s4 = baseH4 + (((T - (i + 2) * 32) * CC) >> 2);
                f0 = s4[l];       f1 = s4[32 + l];  f2 = s4[64 + l];
                f3 = s4[96 + l];  f4 = s4[128 + l]; f5 = s4[160 + l];
                f6 = s4[192 + l]; f7 = s4[224 + l]; f8 = s4[256 + l];
                if (l < 8) f9 = s4[288 + l];
            }
            const int tbase = T - (i + 1) * 32;
            #pragma unroll
            for (int j = 0; j < 16; ++j) { pw[j] = pwp[(31 - j) * CC]; pb[j] = pbp[(31 - j) * CC]; }
            #pragma unroll
            for (int r = 0; r < 32; ++r) {
                const int tt = tbase + 31 - r;
                if (s_ilA == tt + 1 || s_ilB == tt + 1) {   // re-init at t=il-1
                    const bool cond = (il_lane == tt + 1);
                    const float zi = (l == 31 - end_lane || l == 32 - end_lane) ? 1.0f : 0.0f;
                    z    = cond ? zi : z;
                    zx   = cond ? ((end_lane == 32) ? 1.0f : 0.0f) : zx;
                    racc = cond ? 0.0f : racc;
                }
                const float p   = pw[r & 15];
                const float pbv = pb[r & 15];
                if (r < 16) { pw[r & 15] = pwp[(15 - r) * CC]; pb[r & 15] = pbp[(15 - r) * CC]; }
                const float u  = z * p;
                const float uE = zx * pbv;
                float a1, a2;
                SHIFTS(u, uE, a1, a2);
                z  = fmaf(kf, a2, u + a1);
                zx = uE;
                if ((r & 15) == 15) RESCALE(z, zx, racc);
            }
            if (more) {
                float4* d4 = (float4*)Xh;
                d4[l] = f0;       d4[32 + l] = f1;  d4[64 + l] = f2;
                d4[96 + l] = f3;  d4[128 + l] = f4; d4[160 + l] = f5;
                d4[192 + l] = f6; d4[224 + l] = f7; d4[256 + l] = f8;
                if (l < 8) d4[288 + l] = f9;
                __builtin_amdgcn_s_waitcnt(0);
                SOFTMAX(Xw);
                __builtin_amdgcn_s_waitcnt(0);
            }
        }
    }

    // =================== combine + hierarchical finalization ===============
    __syncthreads();
    if (wib == 1) {
        exch[h * 35 + (31 - l)] = z;         // states 31..0
        if (l == 0) { exch[h * 35 + 32] = zx; exch[h * 35 + 33] = racc; }
    }
    __syncthreads();
    if (wib == 0) {
        const float bs = exch[h * 35 + l + 1];            // beta at my state
        float prod = z * bs + (cz0 ? zx * exch[h * 35] : 0.0f);
        #pragma unroll
        for (int o = 16; o > 0; o >>= 1) prod += __shfl_xor(prod, o);  // per-half
        const float rb = exch[h * 35 + 33];
        int i1 = (lane & 32) + end_lane - 1;
        if (i1 < 0) i1 = 0;
        int i2 = i1 - 1;
        if (i2 < 0) i2 = 0;
        const float e1 = __shfl(capv, i1);
        const float e2 = __shfl(capv, i2);
        const float fcap = logaddexp_f(e1, e2);
        const float fmid = __logf(fmaxf(prod, 1e-37f)) + racc + rb
                           - (float)il_lane * LOG37;
        const float final_v = (il_lane <= halfT) ? fcap : fmid;
        const float myloss = cz0 ? (-final_v / (float)tl_lane) : 0.0f; // lanes 0,32
        const float otherloss = __shfl(myloss, 32);
        if (lane == 0) {
            const float pairloss = myloss + otherloss;
            double* slots = ws_d;                        // [64]
            double* gsum  = ws_d + 64;
            int*    bcnt  = (int*)(ws_d + 65);           // [64]
            int*    gcnt  = bcnt + 64;
            const int grid   = (int)gridDim.x;
            const int NB     = (grid < 64) ? grid : 64;
            const int bucket = (int)blockIdx.x % NB;
            atomicAdd(&slots[bucket], (double)pairloss);
            __threadfence();
            const int expected = (grid - bucket + NB - 1) / NB; // blocks in bucket
            const int c = atomicAdd(&bcnt[bucket], 1);
            if (c == expected - 1) {                     // last in bucket
                const double tot = atomicAdd(&slots[bucket], 0.0);
                atomicAdd(gsum, tot);
                __threadfence();
                const int d = atomicAdd(gcnt, 1);
                if (d == NB - 1) {                       // last bucket done
                    const double s = atomicAdd(gsum, 0.0);
                    out[0] = (float)(s / (double)B);
                }
            }
        }
    }
}

// ============ FAST PATH v1 (proven, one sample/block; for 16<L<=31) ========
__global__ __launch_bounds__(128, 4) void ctc_fused_ab_kernel(
    const float* __restrict__ logits,        // [B, T, C]
    const int*   __restrict__ targets,       // [B * L]
    const int*   __restrict__ input_lengths, // [B]
    const int*   __restrict__ target_lengths,// [B]
    float*       __restrict__ per_sample,    // [B]
    int B, int T, int L)
{
    __shared__ float lds[2 * 2368 + 66];
    const int lane = threadIdx.x & 63;
    const int wib  = threadIdx.x >> 6;       // 0 = alpha, 1 = beta
    const int b    = blockIdx.x;

    float* Xw   = lds + wib * 2368;          // this wave's chunk buffer
    float* exch = lds + 4736;                // combine exchange (65 floats)

    const int S = 2 * L + 1;
    const int tlen_s = __builtin_amdgcn_readfirstlane(target_lengths[b]);
    const int ilen_s = __builtin_amdgcn_readfirstlane(input_lengths[b]);
    const int end_s  = 2 * tlen_s;
    const int halfT  = T >> 1;
    const int NC     = T >> 6;               // 64-row chunks (NC even)
    const int NCh    = NC >> 1;              // chunks per wave

    // per-wave state<->lane mapping: alpha natural, beta reversed
    const int st = (wib == 0) ? lane : (63 - lane);
    int ext_w = BLANK;
    if (st < S && (st & 1)) ext_w = targets[b * L + (st >> 1)];
    const int exo = __shfl_up(ext_w, 2);     // alpha: ext[st-2]; beta: ext[st+2]
    float kf;
    if (wib == 0)
        kf = ((st >= 2) && (st < S) && (ext_w != BLANK) && (ext_w != exo)) ? 1.0f : 0.0f;
    else
        kf = ((st + 2 < S) && (exo != BLANK) && (exo != ext_w)) ? 1.0f : 0.0f;

    // row-boundary lanes for the DPP shift patches (verified R10-R12)
    const bool c16 = ((lane & 31) == 16);
    const bool c17 = ((lane & 31) == 17);
    const bool c32 = (lane == 32);
    const bool c33 = (lane == 33);

    const float4* src = (const float4*)(logits + (size_t)b * T * CC);

    // shifted neighbors (x[l-1], x[l-2]) with row-boundary patches
    auto SHIFTS = [&](float x, float& a1, float& a2) {
        const int xi  = __float_as_int(x);
        const int s1  = DPP0(xi, 0x111);
        const int s2  = DPP0(xi, 0x112);
        const int b15 = DPP0(xi, 0x142);
        const int b31 = DPP0(xi, 0x143);
        const int y15 = DPP0(s1, 0x142);
        const int y31 = DPP0(s1, 0x143);
        a1 = __int_as_float(c16 ? b15 : (c32 ? b31 : s1));
        a2 = __int_as_float(c16 ? y15 : (c17 ? b15 : (c32 ? y31 : (c33 ? b31 : s2))));
    };

    auto RESCALE = [&](float& x, float& racc) {  // DPP reduce + readlane
        float m = x;
        m = fmaxf(m, __int_as_float(DPPM(__float_as_int(m), __float_as_int(m), 0x111)));
        m = fmaxf(m, __int_as_float(DPPM(__float_as_int(m), __float_as_int(m), 0x112)));
        m = fmaxf(m, __int_as_float(DPPM(__float_as_int(m), __float_as_int(m), 0x114)));
        m = fmaxf(m, __int_as_float(DPPM(__float_as_int(m), __float_as_int(m), 0x118)));
        m = fmaxf(m, __int_as_float(DPPM(__float_as_int(m), __float_as_int(m), 0x142)));
        m = fmaxf(m, __int_as_float(DPPM(__float_as_int(m), __float_as_int(m), 0x143)));
        float gm = __int_as_float(__builtin_amdgcn_readlane(__float_as_int(m), 63));
        gm = fmaxf(gm, 1e-30f);
        x *= (1.0f / gm);
        racc += __logf(gm);
    };

    auto SOFTMAX = [&](float* Xn) {          // in-place row softmax scaled by 37
        float xr[CC];
        const float* row = Xn + lane * CC;
        #pragma unroll
        for (int c2 = 0; c2 < CC; ++c2) xr[c2] = row[c2];
        float m = xr[0];
        #pragma unroll
        for (int c2 = 1; c2 < CC; ++c2) m = fmaxf(m, xr[c2]);
        float ss = 0.0f;
        #pragma unroll
        for (int c2 = 0; c2 < CC; ++c2) { xr[c2] = __expf(xr[c2] - m); ss += xr[c2]; }
        const float inv = 37.0f / ss;
        float* wrow = Xn + lane * CC;
        #pragma unroll
        for (int c2 = 0; c2 < CC; ++c2) wrow[c2] = xr[c2] * inv;
    };

    auto STAGE = [&](const float4* s2g) {    // global -> this wave's buffer
        float4* dst = (float4*)Xw;
        #pragma unroll
        for (int k = 0; k < 9; ++k) dst[k * 64 + lane] = s2g[k * 64 + lane];
        if (lane < 16) dst[576 + lane] = s2g[576 + lane];
        __builtin_amdgcn_s_waitcnt(0);
    };

    float z = 0.0f, racc = 0.0f, capv = NEG; // z: alpha (w0) / beta (w1)
    float pw[16];

    if (wib == 0) {
        // =================== ALPHA: t = 0 .. halfT-1 =======================
        STAGE(src);
        SOFTMAX(Xw);
        __builtin_amdgcn_s_waitcnt(0);
        #pragma unroll 1
        for (int c = 0; c < NCh; ++c) {
            const bool more = (c + 1 < NCh);
            float4 f0 = {}, f1 = {}, f2 = {}, f3 = {}, f4 = {},
                   f5 = {}, f6 = {}, f7 = {}, f8 = {}, f9 = {};
            if (more) {
                const float4* s2g = src + (size_t)(c + 1) * 592;
                f0 = s2g[lane];       f1 = s2g[64 + lane];  f2 = s2g[128 + lane];
                f3 = s2g[192 + lane]; f4 = s2g[256 + lane]; f5 = s2g[320 + lane];
                f6 = s2g[384 + lane]; f7 = s2g[448 + lane]; f8 = s2g[512 + lane];
                if (lane < 16) f9 = s2g[576 + lane];
            }
            const int tbase = c << 6;
            #pragma unroll
            for (int j = 0; j < 16; ++j) pw[j] = Xw[j * CC + ext_w];
            #pragma unroll
            for (int r = 0; r < 64; ++r) {
                const float p = pw[r & 15];
                if (r + 16 < 64) pw[r & 15] = Xw[(r + 16) * CC + ext_w];
                if (c == 0 && r == 0) {
                    z = (lane <= 1) ? p : 0.0f;
                    if (ilen_s == 1) capv = __logf(fmaxf(z, 1e-35f)) - LOG37;
                } else {
                    float a1, a2;
                    SHIFTS(z, a1, a2);
                    z = fmaf(kf, a2, z + a1) * p;
                    const int tt = tbase + r;
                    if (ilen_s == tt + 1)
                        capv = __logf(fmaxf(z, 1e-35f)) + racc - (float)(tt + 1) * LOG37;
                }
                if ((r & 15) == 15) RESCALE(z, racc);
            }
            if (more) {
                float4* dst = (float4*)Xw;
                dst[lane] = f0;       dst[64 + lane] = f1;  dst[128 + lane] = f2;
                dst[192 + lane] = f3; dst[256 + lane] = f4; dst[320 + lane] = f5;
                dst[384 + lane] = f6; dst[448 + lane] = f7; dst[512 + lane] = f8;
                if (lane < 16) dst[576 + lane] = f9;
                __builtin_amdgcn_s_waitcnt(0);
                SOFTMAX(Xw);
                __builtin_amdgcn_s_waitcnt(0);
            }
        }
    } else {
        // =================== BETA: t = T-1 .. halfT (reversed states) ======
        STAGE(src + (size_t)(NC - 1) * 592);
        SOFTMAX(Xw);
        __builtin_amdgcn_s_waitcnt(0);
        const int il1 = ilen_s - 1;
        #pragma unroll 1
        for (int i = 0; i < NCh; ++i) {
            const bool more = (i + 1 < NCh);
            float4 f0 = {}, f1 = {}, f2 = {}, f3 = {}, f4 = {},
                   f5 = {}, f6 = {}, f7 = {}, f8 = {}, f9 = {};
            if (more) {
                const float4* s2g = src + (size_t)(NC - 2 - i) * 592;
                f0 = s2g[lane];       f1 = s2g[64 + lane];  f2 = s2g[128 + lane];
                f3 = s2g[192 + lane]; f4 = s2g[256 + lane]; f5 = s2g[320 + lane];
                f6 = s2g[384 + lane]; f7 = s2g[448 + lane]; f8 = s2g[512 + lane];
                if (lane < 16) f9 = s2g[576 + lane];
            }
            const int cbase = (NC - 1 - i) << 6;
            #pragma unroll
            for (int j = 0; j < 16; ++j) pw[j] = Xw[(63 - j) * CC + ext_w];
            #pragma unroll
            for (int r = 0; r < 64; ++r) {
                const int tt = cbase + 63 - r;
                if (tt == il1) {                 // wave-uniform re-init
                    z = (lane == 63 - end_s || lane == 64 - end_s) ? 1.0f : 0.0f;
                    racc = 0.0f;
                }
                const float p = pw[r & 15];
                if (r + 16 < 64) pw[r & 15] = Xw[(63 - (r + 16)) * CC + ext_w];
                const float u = z * p;
                float a1, a2;
                SHIFTS(u, a1, a2);
                z = fmaf(kf, a2, u + a1);
                if ((r & 15) == 15) RESCALE(z, racc);
            }
            if (more) {
                float4* dst = (float4*)Xw;
                dst[lane] = f0;       dst[64 + lane] = f1;  dst[128 + lane] = f2;
                dst[192 + lane] = f3; dst[256 + lane] = f4; dst[320 + lane] = f5;
                dst[384 + lane] = f6; dst[448 + lane] = f7; dst[512 + lane] = f8;
                if (lane < 16) dst[576 + lane] = f9;
                __builtin_amdgcn_s_waitcnt(0);
                SOFTMAX(Xw);
                __builtin_amdgcn_s_waitcnt(0);
            }
        }
    }

    // =================== combine ==========================================
    __syncthreads();
    if (wib == 1) {
        exch[63 - lane] = z;                 // exch[state] = beta_tm[state]
        if (lane == 0) exch[64] = racc;
    }
    __syncthreads();
    if (wib == 0) {
        const float bs = exch[lane];         // beta at my state (0 if invalid)
        const float rb = exch[64];
        float prod = z * bs;                 // garbage alpha lanes x 0 = 0
        #pragma unroll
        for (int o = 32; o > 0; o >>= 1) prod += __shfl_xor(prod, o);
        float final_v;
        if (ilen_s <= halfT) {               // alpha capture path
            const float e1 = __shfl(capv, end_s);
            const float e2 = __shfl(capv, end_s - 1);
            final_v = logaddexp_f(e1, e2);
        } else {                             // midpoint product path
            final_v = __logf(fmaxf(prod, 1e-37f)) + racc + rb - (float)ilen_s * LOG37;
        }
        if (lane == 0) per_sample[b] = -final_v / (float)tlen_s;
    }
}

// ============ FALLBACK PATH (proven R2 kernels) ============================
__global__ __launch_bounds__(256) void lse_kernel(
    const float* __restrict__ logits, float* __restrict__ denom, int N)
{
    __shared__ float lds[256 * CC];
    const int lane = threadIdx.x & 63;
    const int wib  = threadIdx.x >> 6;
    const int wave = blockIdx.x * 4 + wib;
    const long long row0 = (long long)wave * 64;
    if (row0 >= N) return;
    const int wbase = wib * 64 * CC;
    const float4* src4 = (const float4*)(logits + row0 * CC);
    const long long n4_remaining = ((long long)N * CC - row0 * CC) / 4;
    float4* lds4 = (float4*)(lds + wbase);
    #pragma unroll
    for (int k = 0; k < 10; ++k) {
        const int idx = k * 64 + lane;
        if (idx < 592 && idx < n4_remaining) lds4[idx] = src4[idx];
    }
    __builtin_amdgcn_s_waitcnt(0);
    const long long row = row0 + lane;
    if (row >= N) return;
    const float* x = lds + wbase + lane * CC;
    float m = x[0];
    #pragma unroll
    for (int c = 1; c < CC; ++c) m = fmaxf(m, x[c]);
    float s = 0.0f;
    #pragma unroll
    for (int c = 0; c < CC; ++c) s += __expf(x[c] - m);
    denom[row] = m + __logf(s);
}

__global__ __launch_bounds__(256) void ctc_alpha2_kernel(
    const float* __restrict__ logits, const float* __restrict__ denom,
    const int* __restrict__ targets, const int* __restrict__ input_lengths,
    const int* __restrict__ target_lengths, float* __restrict__ per_sample,
    int B, int T, int L)
{
    const int wave = (int)((blockIdx.x * blockDim.x + threadIdx.x) >> 6);
    const int lane = threadIdx.x & 63;
    if (wave >= B) return;
    const int b = wave;
    const int S = 2 * L + 1;
    const int tlen = target_lengths[b];
    const int ilen = input_lengths[b];
    const int end_idx = 2 * tlen;
    int ext_s = BLANK;
    if (lane < S && (lane & 1)) ext_s = targets[b * L + (lane >> 1)];
    const int ext_sm2 = __shfl_up(ext_s, 2);
    const bool skip_ok = (lane < S) && (lane >= 2) && (ext_s != BLANK) && (ext_s != ext_sm2);
    const bool valid = lane < (2 * tlen + 1);
    const float* lg = logits + (size_t)b * T * CC;
    const float* dn = denom + (size_t)b * T;
    float x_cur = lg[ext_s];
    float d_cur = dn[0];
    float x_nx = (T > 1) ? lg[CC + ext_s] : 0.0f;
    float d_nx = (T > 1) ? dn[1] : 0.0f;
    float final_v = NEG;
    float alpha = (valid && lane <= 1) ? (x_cur - d_cur) : NEG;
    if (ilen == 1) {
        const float e1 = __shfl(alpha, end_idx);
        const float e2 = __shfl(alpha, end_idx - 1);
        final_v = logaddexp_f(e1, e2);
    }
    for (int tt = 1; tt < T; ++tt) {
        x_cur = x_nx; d_cur = d_nx;
        if (tt + 1 < T) {
            x_nx = lg[(size_t)(tt + 1) * CC + ext_s];
            d_nx = dn[tt + 1];
        }
        const float lpe = x_cur - d_cur;
        float a1 = __shfl_up(alpha, 1);
        if (lane == 0) a1 = NEG;
        float a2 = __shfl_up(alpha, 2);
        if (!skip_ok) a2 = NEG;
        const float m = fmaxf(fmaxf(alpha, a1), a2);
        const float s = __expf(alpha - m) + __expf(a1 - m) + __expf(a2 - m);
        const float na = m + __logf(s) + lpe;
        alpha = valid ? na : NEG;
        if (ilen == tt + 1) {
            const float e1 = __shfl(alpha, end_idx);
            const float e2 = __shfl(alpha, end_idx - 1);
            final_v = logaddexp_f(e1, e2);
        }
    }
    if (lane == 0) per_sample[b] = -final_v / (float)tlen;
}

__global__ __launch_bounds__(256) void ctc_alpha_mono_kernel(
    const float* __restrict__ logits, const int* __restrict__ targets,
    const int* __restrict__ input_lengths, const int* __restrict__ target_lengths,
    float* __restrict__ per_sample, int B, int T, int L)
{
    const int wave = (int)((blockIdx.x * blockDim.x + threadIdx.x) >> 6);
    const int lane = threadIdx.x & 63;
    if (wave >= B) return;
    const int b = wave;
    const int S = 2 * L + 1;
    const int tlen = target_lengths[b];
    const int ilen = input_lengths[b];
    const int end_idx = 2 * tlen;
    int ext_s = BLANK;
    if (lane < S && (lane & 1)) ext_s = targets[b * L + (lane >> 1)];
    const int ext_sm2 = __shfl_up(ext_s, 2);
    const bool skip_ok = (lane < S) && (lane >= 2) && (ext_s != BLANK) && (ext_s != ext_sm2);
    const bool valid = lane < (2 * tlen + 1);
    const float* lg = logits + (size_t)b * T * CC;
    float alpha = NEG, final_v = NEG;
    for (int t = 0; t < T; ++t) {
        float x = (lane < CC) ? lg[t * CC + lane] : -3.0e38f;
        float mx = x;
        #pragma unroll
        for (int o = 32; o > 0; o >>= 1) mx = fmaxf(mx, __shfl_xor(mx, o));
        float e = (lane < CC) ? __expf(x - mx) : 0.0f;
        float se = e;
        #pragma unroll
        for (int o = 32; o > 0; o >>= 1) se += __shfl_xor(se, o);
        const float lp = x - mx - __logf(se);
        const float lpe = __shfl(lp, ext_s);
        float newa;
        if (t == 0) {
            newa = (lane <= 1) ? lpe : NEG;
        } else {
            float a1 = __shfl_up(alpha, 1);
            if (lane == 0) a1 = NEG;
            float a2 = __shfl_up(alpha, 2);
            if (!skip_ok) a2 = NEG;
            newa = logaddexp_f(logaddexp_f(alpha, a1), a2) + lpe;
        }
        if (!valid) newa = NEG;
        alpha = newa;
        if (ilen == t + 1) {
            const float e1 = __shfl(alpha, end_idx);
            const float e2 = __shfl(alpha, end_idx - 1);
            final_v = logaddexp_f(e1, e2);
        }
    }
    if (lane == 0) per_sample[b] = -final_v / (float)tlen;
}

// ---------------- Deterministic mean over B samples (fallback paths) -------
__global__ __launch_bounds__(256) void reduce_mean_kernel(
    const float* __restrict__ ps, float* __restrict__ out, int B)
{
    float s = 0.0f;
    for (int i = threadIdx.x; i < B; i += 256) s += ps[i];
    #pragma unroll
    for (int o = 32; o > 0; o >>= 1) s += __shfl_xor(s, o);
    __shared__ float sm[4];
    const int w = threadIdx.x >> 6, l = threadIdx.x & 63;
    if (l == 0) sm[w] = s;
    __syncthreads();
    if (threadIdx.x == 0) {
        out[0] = (sm[0] + sm[1] + sm[2] + sm[3]) / (float)B;
    }
}

extern "C" void kernel_launch(void* const* d_in, const int* in_sizes, int n_in,
                              void* d_out, int out_size, void* d_ws, size_t ws_size,
                              hipStream_t stream) {
    const float* logits         = (const float*)d_in[0];
    const int*   targets        = (const int*)d_in[1];
    const int*   input_lengths  = (const int*)d_in[2];
    const int*   target_lengths = (const int*)d_in[3];

    const int B = in_sizes[2];
    const int L = in_sizes[1] / B;
    const int T = in_sizes[0] / (B * CC);
    const long long N = (long long)B * T;

    float* per_sample = (float*)d_ws;
    float* scratch    = per_sample + B;
    float* out        = (float*)d_out;

    const size_t ws_mid = ((size_t)B + (size_t)N) * sizeof(float);
    const int nblocks_alpha = (B * 64 + 255) / 256;
    const long long nwaves = (N + 63) / 64;

    const bool fast2 = (B % 2 == 0) && (T % 64 == 0) && T >= 64 && L <= 16 &&
                       ws_size >= 1024;
    const bool fast1 = (T % 128 == 0) && T >= 128 && L <= 31 &&
                       ws_size >= (size_t)B * sizeof(float);

    if (fast2) {
        // ws: 64 double slots + global double + 64+1 int counters (zeroed)
        hipMemsetAsync(d_ws, 0, 1024, stream);
        ctc_fused_ab2_kernel<<<B / 2, 128, 0, stream>>>(
            logits, targets, input_lengths, target_lengths,
            (double*)d_ws, out, B, T, L);
    } else if (fast1) {
        ctc_fused_ab_kernel<<<B, 128, 0, stream>>>(
            logits, targets, input_lengths, target_lengths, per_sample, B, T, L);
        reduce_mean_kernel<<<1, 256, 0, stream>>>(per_sample, out, B);
    } else if (ws_size >= ws_mid && T >= 2) {
        lse_kernel<<<(int)((nwaves + 3) / 4), 256, 0, stream>>>(logits, scratch, (int)N);
        ctc_alpha2_kernel<<<nblocks_alpha, 256, 0, stream>>>(
            logits, scratch, targets, input_lengths, target_lengths, per_sample, B, T, L);
        reduce_mean_kernel<<<1, 256, 0, stream>>>(per_sample, out, B);
    } else {
        ctc_alpha_mono_kernel<<<nblocks_alpha, 256, 0, stream>>>(
            logits, targets, input_lengths, target_lengths, per_sample, B, T, L);
        reduce_mean_kernel<<<1, 256, 0, stream>>>(per_sample, out, B);
    }
}

// Round 4
// 117.333 us; speedup vs baseline: 1.1665x; 1.1418x over previous
//
#include <hip/hip_runtime.h>

#define BLANK 36
#define NEG -1e30f
#define CC 37
#define LOG37 3.6109179126442243f

__device__ __forceinline__ float logaddexp_f(float a, float b) {
    float m = fmaxf(a, b);
    float d = fabsf(a - b);
    return m + __logf(1.0f + __expf(-d));
}

// DPP helpers (VALU pipe): 0x110|n = row_shr:n, 0x142 = row_bcast15,
// 0x143 = row_bcast31. bound_ctrl=true -> OOB lanes read 0.
#define DPP0(src, ctrl) __builtin_amdgcn_update_dpp(0, (src), (ctrl), 0xf, 0xf, true)
#define DPPM(old, src, ctrl) __builtin_amdgcn_update_dpp((old), (src), (ctrl), 0xf, 0xf, false)

// Async global->LDS, 16B per lane. Dest = wave-uniform base + lane*16 (m104);
// global source address is per-lane (m173).
__device__ __forceinline__ void gl_lds16(const float4* g, float* l) {
    __builtin_amdgcn_global_load_lds(
        (const __attribute__((address_space(1))) void*)g,
        (__attribute__((address_space(3))) void*)l,
        16, 0, 0);
}

// ============ FAST PATH v5: two samples/wave + async LDS double-buffer =====
// R16: R15 profile showed VGPR_Count=56 -> compiler SANK the 10xfloat4
// register-staged chunk loads to the consumption point (can't hold 40 VGPRs
// across the unrolled 32-step loop) -> each chunk exposed serialized
// L3/HBM latency; kernel ~49us compute at VALUBusy ~15-20% (80% stall).
// Fix: global_load_lds (zero VGPRs) into a double-buffered LDS chunk,
// issued BEFORE the 32-step recurrence so latency hides under compute.
// LDS stays linear; per-lane global src steers slot s=k*64+lane:
// s<296 -> sample A float4 s, else sample B float4 s-296. Tail lane<16.
// LDS/block: 2 waves x 2 bufs x 2368 floats + 72 = 38.2KB -> 4 blocks/CU,
// which equals the grid limit (B/2=1024 blocks / 256 CU). Finalize reverted
// to per_sample + reduce_mean (R13 proven; R14/R15 device-scope atomic
// finalize cost ~16us in cross-XCD coherence traffic).
__global__ __launch_bounds__(128, 2) void ctc_fused_ab2_kernel(
    const float* __restrict__ logits,        // [B, T, C]
    const int*   __restrict__ targets,       // [B * L]
    const int*   __restrict__ input_lengths, // [B]
    const int*   __restrict__ target_lengths,// [B]
    float*       __restrict__ per_sample,    // [B]
    int B, int T, int L)
{
    __shared__ float lds[2 * 4736 + 72];
    const int lane = threadIdx.x & 63;
    const int wib  = threadIdx.x >> 6;       // 0 = alpha, 1 = beta
    const int h    = lane >> 5;              // sample within pair
    const int l    = lane & 31;              // per-sample lane
    const int b0   = blockIdx.x * 2;
    const int bme  = b0 + h;

    float* Xw   = lds + wib * 4736;          // this wave's two chunk buffers
    float* exch = lds + 9472;                // combine exchange (2x35)

    const int halfT = T >> 1;
    const int NCh   = halfT >> 5;            // 32-row chunks per wave
    const int NCtot = T >> 5;                // total 32-row chunks per sample

    const int tl_lane  = target_lengths[bme];
    const int il_lane  = input_lengths[bme];
    const int end_lane = 2 * tl_lane;
    const int s_ilA = __builtin_amdgcn_readlane(il_lane, 0);
    const int s_ilB = __builtin_amdgcn_readlane(il_lane, 32);

    // ext for my state: alpha lane l = state l+1; beta lane l = state 31-l.
    // Odd state <=> even l. Clamp target index for L<16 memory safety (only
    // affects invalid states).
    int ext_w = BLANK;
    if (!(l & 1)) {
        int ti = (wib == 0) ? (l >> 1) : (15 - (l >> 1));
        if (ti >= L) ti = L - 1;
        if (ti < 0) ti = 0;
        ext_w = targets[bme * L + ti];
    }
    const int exo = __shfl_up(ext_w, 2);     // within-half for l>=2 (guarded)
    float kf;
    if (wib == 0)   // skip into state s=l+1 from s-2 (lane l-2)
        kf = (l >= 2 && ext_w != BLANK && ext_w != exo) ? 1.0f : 0.0f;
    else            // skip from state s=31-l to s+2 (lane l-2)
        kf = ((33 - l) <= 2 * L && exo != BLANK && exo != ext_w) ? 1.0f : 0.0f;

    const bool c16 = (l == 16);              // lanes 16, 48 (in-half row bnd)
    const bool c17 = (l == 17);              // lanes 17, 49
    const bool cz0 = (l == 0);               // lanes 0, 32 (zx injection)
    const int bcast_addr = (((lane & 32) | 31) << 2);   // half-bcast source

    const float4* gA4 = (const float4*)(logits + (size_t)b0 * T * CC);
    const float4* gB4 = (const float4*)(logits + (size_t)(b0 + 1) * T * CC);

    auto SHIFTS = [&](float x, float inj, float& a1, float& a2) {
        const int xi  = __float_as_int(x);
        const int s1  = DPP0(xi, 0x111);
        const int s2  = DPP0(xi, 0x112);
        const int b15 = DPP0(xi, 0x142);
        const int y15 = DPP0(s1, 0x142);
        a1 = cz0 ? inj : __int_as_float(c16 ? b15 : s1);
        a2 = __int_as_float(c16 ? y15 : (c17 ? b15 : s2));
    };

    auto RESCALE = [&](float& x, float& x2, float& racc) {
        float m = fmaxf(x, x2);
        m = fmaxf(m, __int_as_float(DPPM(__float_as_int(m), __float_as_int(m), 0x111)));
        m = fmaxf(m, __int_as_float(DPPM(__float_as_int(m), __float_as_int(m), 0x112)));
        m = fmaxf(m, __int_as_float(DPPM(__float_as_int(m), __float_as_int(m), 0x114)));
        m = fmaxf(m, __int_as_float(DPPM(__float_as_int(m), __float_as_int(m), 0x118)));
        m = fmaxf(m, __int_as_float(DPPM(__float_as_int(m), __float_as_int(m), 0x142)));
        // lane 31 holds max(0..31), lane 63 max(32..63); broadcast per half
        float gm = __int_as_float(__builtin_amdgcn_ds_bpermute(bcast_addr, __float_as_int(m)));
        gm = fmaxf(gm, 1e-30f);
        const float inv = __builtin_amdgcn_rcpf(gm);
        x *= inv; x2 *= inv;
        racc += __logf(gm);
    };

    auto SOFTMAX = [&](float* Xn) {          // 64 rows (2 samples x 32), x37
        float xr[CC];
        const float* row = Xn + lane * CC;
        #pragma unroll
        for (int c2 = 0; c2 < CC; ++c2) xr[c2] = row[c2];
        float m = xr[0];
        #pragma unroll
        for (int c2 = 1; c2 < CC; ++c2) m = fmaxf(m, xr[c2]);
        float ss = 0.0f;
        #pragma unroll
        for (int c2 = 0; c2 < CC; ++c2) { xr[c2] = __expf(xr[c2] - m); ss += xr[c2]; }
        const float inv = 37.0f / ss;
        float* wrow = Xn + lane * CC;
        #pragma unroll
        for (int c2 = 0; c2 < CC; ++c2) wrow[c2] = xr[c2] * inv;
    };

    // Async stage one 32-row chunk-pair (A then B, linear LDS) into dst.
    // coff4 = chunk index * 296 (float4 offset within each sample).
    auto STAGE_ASYNC = [&](float* dst, int coff4) {
        #pragma unroll
        for (int k = 0; k < 9; ++k) {
            const int s = k * 64 + lane;
            const float4* src = (s < 296) ? (gA4 + coff4 + s)
                                          : (gB4 + coff4 + (s - 296));
            gl_lds16(src, dst + k * 256);
        }
        if (lane < 16) {
            gl_lds16(gB4 + coff4 + (280 + lane), dst + 2304);  // slots 576..591
        }
    };

    float z = 0.0f, zx = 0.0f, racc = 0.0f, capv = NEG;
    float pw[16], pb[16];

    float* cur = Xw;
    float* nxt = Xw + 2368;

    if (wib == 0) {
        // =================== ALPHA: t = 0 .. halfT-1 =======================
        STAGE_ASYNC(cur, 0);
        __builtin_amdgcn_s_waitcnt(0);
        SOFTMAX(cur);
        __builtin_amdgcn_s_waitcnt(0);
        #pragma unroll 1
        for (int c = 0; c < NCh; ++c) {
            const bool more = (c + 1 < NCh);
            if (more) STAGE_ASYNC(nxt, (c + 1) * 296);   // issue EARLY, 0 VGPR
            const float* pwp = cur + h * 1184 + ext_w;
            const float* pbp = cur + h * 1184 + 36;
            #pragma unroll
            for (int j = 0; j < 16; ++j) { pw[j] = pwp[j * CC]; pb[j] = pbp[j * CC]; }
            #pragma unroll
            for (int r = 0; r < 32; ++r) {
                const float p   = pw[r & 15];
                const float pbv = pb[r & 15];
                if (r < 16) { pw[r & 15] = pwp[(r + 16) * CC]; pb[r & 15] = pbp[(r + 16) * CC]; }
                if (c == 0 && r == 0) {
                    z  = cz0 ? p : 0.0f;     // state 1
                    zx = pbv;                // state 0 (blank)
                } else {
                    float a1, a2;
                    SHIFTS(z, zx, a1, a2);   // inject state0 at lane 0/32
                    z = fmaf(kf, a2, z + a1) * p;
                    zx *= pbv;
                }
                const int tt = (c << 5) + r;
                if (s_ilA == tt + 1 || s_ilB == tt + 1) {
                    const float cv = __logf(fmaxf(z, 1e-35f)) + racc - (float)(tt + 1) * LOG37;
                    capv = (il_lane == tt + 1) ? cv : capv;
                }
                if ((r & 15) == 15) RESCALE(z, zx, racc);
            }
            if (more) {
                __builtin_amdgcn_s_waitcnt(0);           // loads landed in nxt
                SOFTMAX(nxt);
                __builtin_amdgcn_s_waitcnt(0);
                float* t = cur; cur = nxt; nxt = t;
            }
        }
    } else {
        // =================== BETA: t = T-1 .. halfT (states reversed) ======
        // lane l = state 31-l; zx = state 32 (tail blank): zx *= p_blank,
        // injects u[32] into lane 0/32's a1. Invalid states (> end) stay
        // exactly 0 (fed only from higher invalid states).
        STAGE_ASYNC(cur, (NCtot - 1) * 296);
        __builtin_amdgcn_s_waitcnt(0);
        SOFTMAX(cur);
        __builtin_amdgcn_s_waitcnt(0);
        #pragma unroll 1
        for (int i = 0; i < NCh; ++i) {
            const bool more = (i + 1 < NCh);
            if (more) STAGE_ASYNC(nxt, (NCtot - 2 - i) * 296);
            const float* pwp = cur + h * 1184 + ext_w;
            const float* pbp = cur + h * 1184 + 36;
            const int tbase = T - (i + 1) * 32;
            #pragma unroll
            for (int j = 0; j < 16; ++j) { pw[j] = pwp[(31 - j) * CC]; pb[j] = pbp[(31 - j) * CC]; }
            #pragma unroll
            for (int r = 0; r < 32; ++r) {
                const int tt = tbase + 31 - r;
                if (s_ilA == tt + 1 || s_ilB == tt + 1) {   // re-init at t=il-1
                    const bool cond = (il_lane == tt + 1);
                    const float zi = (l == 31 - end_lane || l == 32 - end_lane) ? 1.0f : 0.0f;
                    z    = cond ? zi : z;
                    zx   = cond ? ((end_lane == 32) ? 1.0f : 0.0f) : zx;
                    racc = cond ? 0.0f : racc;
                }
                const float p   = pw[r & 15];
                const float pbv = pb[r & 15];
                if (r < 16) { pw[r & 15] = pwp[(15 - r) * CC]; pb[r & 15] = pbp[(15 - r) * CC]; }
                const float u  = z * p;
                const float uE = zx * pbv;
                float a1, a2;
                SHIFTS(u, uE, a1, a2);
                z  = fmaf(kf, a2, u + a1);
                zx = uE;
                if ((r & 15) == 15) RESCALE(z, zx, racc);
            }
            if (more) {
                __builtin_amdgcn_s_waitcnt(0);
                SOFTMAX(nxt);
                __builtin_amdgcn_s_waitcnt(0);
                float* t = cur; cur = nxt; nxt = t;
            }
        }
    }

    // =================== combine ==========================================
    __syncthreads();
    if (wib == 1) {
        exch[h * 35 + (31 - l)] = z;         // states 31..0
        if (l == 0) { exch[h * 35 + 32] = zx; exch[h * 35 + 33] = racc; }
    }
    __syncthreads();
    if (wib == 0) {
        const float bs = exch[h * 35 + l + 1];            // beta at my state
        float prod = z * bs + (cz0 ? zx * exch[h * 35] : 0.0f);
        #pragma unroll
        for (int o = 16; o > 0; o >>= 1) prod += __shfl_xor(prod, o);  // per-half
        const float rb = exch[h * 35 + 33];
        int i1 = (lane & 32) + end_lane - 1;
        if (i1 < 0) i1 = 0;
        int i2 = i1 - 1;
        if (i2 < 0) i2 = 0;
        const float e1 = __shfl(capv, i1);
        const float e2 = __shfl(capv, i2);
        const float fcap = logaddexp_f(e1, e2);
        const float fmid = __logf(fmaxf(prod, 1e-37f)) + racc + rb
                           - (float)il_lane * LOG37;
        const float final_v = (il_lane <= halfT) ? fcap : fmid;
        if (l == 0) per_sample[bme] = -final_v / (float)tl_lane;
    }
}

// ============ FAST PATH v1 (proven, one sample/block; for 16<L<=31) ========
__global__ __launch_bounds__(128, 4) void ctc_fused_ab_kernel(
    const float* __restrict__ logits,        // [B, T, C]
    const int*   __restrict__ targets,       // [B * L]
    const int*   __restrict__ input_lengths, // [B]
    const int*   __restrict__ target_lengths,// [B]
    float*       __restrict__ per_sample,    // [B]
    int B, int T, int L)
{
    __shared__ float lds[2 * 2368 + 66];
    const int lane = threadIdx.x & 63;
    const int wib  = threadIdx.x >> 6;       // 0 = alpha, 1 = beta
    const int b    = blockIdx.x;

    float* Xw   = lds + wib * 2368;          // this wave's chunk buffer
    float* exch = lds + 4736;                // combine exchange (65 floats)

    const int S = 2 * L + 1;
    const int tlen_s = __builtin_amdgcn_readfirstlane(target_lengths[b]);
    const int ilen_s = __builtin_amdgcn_readfirstlane(input_lengths[b]);
    const int end_s  = 2 * tlen_s;
    const int halfT  = T >> 1;
    const int NC     = T >> 6;               // 64-row chunks (NC even)
    const int NCh    = NC >> 1;              // chunks per wave

    // per-wave state<->lane mapping: alpha natural, beta reversed
    const int st = (wib == 0) ? lane : (63 - lane);
    int ext_w = BLANK;
    if (st < S && (st & 1)) ext_w = targets[b * L + (st >> 1)];
    const int exo = __shfl_up(ext_w, 2);     // alpha: ext[st-2]; beta: ext[st+2]
    float kf;
    if (wib == 0)
        kf = ((st >= 2) && (st < S) && (ext_w != BLANK) && (ext_w != exo)) ? 1.0f : 0.0f;
    else
        kf = ((st + 2 < S) && (exo != BLANK) && (exo != ext_w)) ? 1.0f : 0.0f;

    // row-boundary lanes for the DPP shift patches (verified R10-R12)
    const bool c16 = ((lane & 31) == 16);
    const bool c17 = ((lane & 31) == 17);
    const bool c32 = (lane == 32);
    const bool c33 = (lane == 33);

    const float4* src = (const float4*)(logits + (size_t)b * T * CC);

    // shifted neighbors (x[l-1], x[l-2]) with row-boundary patches
    auto SHIFTS = [&](float x, float& a1, float& a2) {
        const int xi  = __float_as_int(x);
        const int s1  = DPP0(xi, 0x111);
        const int s2  = DPP0(xi, 0x112);
        const int b15 = DPP0(xi, 0x142);
        const int b31 = DPP0(xi, 0x143);
        const int y15 = DPP0(s1, 0x142);
        const int y31 = DPP0(s1, 0x143);
        a1 = __int_as_float(c16 ? b15 : (c32 ? b31 : s1));
        a2 = __int_as_float(c16 ? y15 : (c17 ? b15 : (c32 ? y31 : (c33 ? b31 : s2))));
    };

    auto RESCALE = [&](float& x, float& racc) {  // DPP reduce + readlane
        float m = x;
        m = fmaxf(m, __int_as_float(DPPM(__float_as_int(m), __float_as_int(m), 0x111)));
        m = fmaxf(m, __int_as_float(DPPM(__float_as_int(m), __float_as_int(m), 0x112)));
        m = fmaxf(m, __int_as_float(DPPM(__float_as_int(m), __float_as_int(m), 0x114)));
        m = fmaxf(m, __int_as_float(DPPM(__float_as_int(m), __float_as_int(m), 0x118)));
        m = fmaxf(m, __int_as_float(DPPM(__float_as_int(m), __float_as_int(m), 0x142)));
        m = fmaxf(m, __int_as_float(DPPM(__float_as_int(m), __float_as_int(m), 0x143)));
        float gm = __int_as_float(__builtin_amdgcn_readlane(__float_as_int(m), 63));
        gm = fmaxf(gm, 1e-30f);
        x *= (1.0f / gm);
        racc += __logf(gm);
    };

    auto SOFTMAX = [&](float* Xn) {          // in-place row softmax scaled by 37
        float xr[CC];
        const float* row = Xn + lane * CC;
        #pragma unroll
        for (int c2 = 0; c2 < CC; ++c2) xr[c2] = row[c2];
        float m = xr[0];
        #pragma unroll
        for (int c2 = 1; c2 < CC; ++c2) m = fmaxf(m, xr[c2]);
        float ss = 0.0f;
        #pragma unroll
        for (int c2 = 0; c2 < CC; ++c2) { xr[c2] = __expf(xr[c2] - m); ss += xr[c2]; }
        const float inv = 37.0f / ss;
        float* wrow = Xn + lane * CC;
        #pragma unroll
        for (int c2 = 0; c2 < CC; ++c2) wrow[c2] = xr[c2] * inv;
    };

    auto STAGE = [&](const float4* s2g) {    // global -> this wave's buffer
        float4* dst = (float4*)Xw;
        #pragma unroll
        for (int k = 0; k < 9; ++k) dst[k * 64 + lane] = s2g[k * 64 + lane];
        if (lane < 16) dst[576 + lane] = s2g[576 + lane];
        __builtin_amdgcn_s_waitcnt(0);
    };

    float z = 0.0f, racc = 0.0f, capv = NEG; // z: alpha (w0) / beta (w1)
    float pw[16];

    if (wib == 0) {
        // =================== ALPHA: t = 0 .. halfT-1 =======================
        STAGE(src);
        SOFTMAX(Xw);
        __builtin_amdgcn_s_waitcnt(0);
        #pragma unroll 1
        for (int c = 0; c < NCh; ++c) {
            const bool more = (c + 1 < NCh);
            float4 f0 = {}, f1 = {}, f2 = {}, f3 = {}, f4 = {},
                   f5 = {}, f6 = {}, f7 = {}, f8 = {}, f9 = {};
            if (more) {
                const float4* s2g = src + (size_t)(c + 1) * 592;
                f0 = s2g[lane];       f1 = s2g[64 + lane];  f2 = s2g[128 + lane];
                f3 = s2g[192 + lane]; f4 = s2g[256 + lane]; f5 = s2g[320 + lane];
                f6 = s2g[384 + lane]; f7 = s2g[448 + lane]; f8 = s2g[512 + lane];
                if (lane < 16) f9 = s2g[576 + lane];
            }
            const int tbase = c << 6;
            #pragma unroll
            for (int j = 0; j < 16; ++j) pw[j] = Xw[j * CC + ext_w];
            #pragma unroll
            for (int r = 0; r < 64; ++r) {
                const float p = pw[r & 15];
                if (r + 16 < 64) pw[r & 15] = Xw[(r + 16) * CC + ext_w];
                if (c == 0 && r == 0) {
                    z = (lane <= 1) ? p : 0.0f;
                    if (ilen_s == 1) capv = __logf(fmaxf(z, 1e-35f)) - LOG37;
                } else {
                    float a1, a2;
                    SHIFTS(z, a1, a2);
                    z = fmaf(kf, a2, z + a1) * p;
                    const int tt = tbase + r;
                    if (ilen_s == tt + 1)
                        capv = __logf(fmaxf(z, 1e-35f)) + racc - (float)(tt + 1) * LOG37;
                }
                if ((r & 15) == 15) RESCALE(z, racc);
            }
            if (more) {
                float4* dst = (float4*)Xw;
                dst[lane] = f0;       dst[64 + lane] = f1;  dst[128 + lane] = f2;
                dst[192 + lane] = f3; dst[256 + lane] = f4; dst[320 + lane] = f5;
                dst[384 + lane] = f6; dst[448 + lane] = f7; dst[512 + lane] = f8;
                if (lane < 16) dst[576 + lane] = f9;
                __builtin_amdgcn_s_waitcnt(0);
                SOFTMAX(Xw);
                __builtin_amdgcn_s_waitcnt(0);
            }
        }
    } else {
        // =================== BETA: t = T-1 .. halfT (reversed states) ======
        STAGE(src + (size_t)(NC - 1) * 592);
        SOFTMAX(Xw);
        __builtin_amdgcn_s_waitcnt(0);
        const int il1 = ilen_s - 1;
        #pragma unroll 1
        for (int i = 0; i < NCh; ++i) {
            const bool more = (i + 1 < NCh);
            float4 f0 = {}, f1 = {}, f2 = {}, f3 = {}, f4 = {},
                   f5 = {}, f6 = {}, f7 = {}, f8 = {}, f9 = {};
            if (more) {
                const float4* s2g = src + (size_t)(NC - 2 - i) * 592;
                f0 = s2g[lane];       f1 = s2g[64 + lane];  f2 = s2g[128 + lane];
                f3 = s2g[192 + lane]; f4 = s2g[256 + lane]; f5 = s2g[320 + lane];
                f6 = s2g[384 + lane]; f7 = s2g[448 + lane]; f8 = s2g[512 + lane];
                if (lane < 16) f9 = s2g[576 + lane];
            }
            const int cbase = (NC - 1 - i) << 6;
            #pragma unroll
            for (int j = 0; j < 16; ++j) pw[j] = Xw[(63 - j) * CC + ext_w];
            #pragma unroll
            for (int r = 0; r < 64; ++r) {
                const int tt = cbase + 63 - r;
                if (tt == il1) {                 // wave-uniform re-init
                    z = (lane == 63 - end_s || lane == 64 - end_s) ? 1.0f : 0.0f;
                    racc = 0.0f;
                }
                const float p = pw[r & 15];
                if (r + 16 < 64) pw[r & 15] = Xw[(63 - (r + 16)) * CC + ext_w];
                const float u = z * p;
                float a1, a2;
                SHIFTS(u, a1, a2);
                z = fmaf(kf, a2, u + a1);
                if ((r & 15) == 15) RESCALE(z, racc);
            }
            if (more) {
                float4* dst = (float4*)Xw;
                dst[lane] = f0;       dst[64 + lane] = f1;  dst[128 + lane] = f2;
                dst[192 + lane] = f3; dst[256 + lane] = f4; dst[320 + lane] = f5;
                dst[384 + lane] = f6; dst[448 + lane] = f7; dst[512 + lane] = f8;
                if (lane < 16) dst[576 + lane] = f9;
                __builtin_amdgcn_s_waitcnt(0);
                SOFTMAX(Xw);
                __builtin_amdgcn_s_waitcnt(0);
            }
        }
    }

    // =================== combine ==========================================
    __syncthreads();
    if (wib == 1) {
        exch[63 - lane] = z;                 // exch[state] = beta_tm[state]
        if (lane == 0) exch[64] = racc;
    }
    __syncthreads();
    if (wib == 0) {
        const float bs = exch[lane];         // beta at my state (0 if invalid)
        const float rb = exch[64];
        float prod = z * bs;                 // garbage alpha lanes x 0 = 0
        #pragma unroll
        for (int o = 32; o > 0; o >>= 1) prod += __shfl_xor(prod, o);
        float final_v;
        if (ilen_s <= halfT) {               // alpha capture path
            const float e1 = __shfl(capv, end_s);
            const float e2 = __shfl(capv, end_s - 1);
            final_v = logaddexp_f(e1, e2);
        } else {                             // midpoint product path
            final_v = __logf(fmaxf(prod, 1e-37f)) + racc + rb - (float)ilen_s * LOG37;
        }
        if (lane == 0) per_sample[b] = -final_v / (float)tlen_s;
    }
}

// ============ FALLBACK PATH (proven R2 kernels) ============================
__global__ __launch_bounds__(256) void lse_kernel(
    const float* __restrict__ logits, float* __restrict__ denom, int N)
{
    __shared__ float lds[256 * CC];
    const int lane = threadIdx.x & 63;
    const int wib  = threadIdx.x >> 6;
    const int wave = blockIdx.x * 4 + wib;
    const long long row0 = (long long)wave * 64;
    if (row0 >= N) return;
    const int wbase = wib * 64 * CC;
    const float4* src4 = (const float4*)(logits + row0 * CC);
    const long long n4_remaining = ((long long)N * CC - row0 * CC) / 4;
    float4* lds4 = (float4*)(lds + wbase);
    #pragma unroll
    for (int k = 0; k < 10; ++k) {
        const int idx = k * 64 + lane;
        if (idx < 592 && idx < n4_remaining) lds4[idx] = src4[idx];
    }
    __builtin_amdgcn_s_waitcnt(0);
    const long long row = row0 + lane;
    if (row >= N) return;
    const float* x = lds + wbase + lane * CC;
    float m = x[0];
    #pragma unroll
    for (int c = 1; c < CC; ++c) m = fmaxf(m, x[c]);
    float s = 0.0f;
    #pragma unroll
    for (int c = 0; c < CC; ++c) s += __expf(x[c] - m);
    denom[row] = m + __logf(s);
}

__global__ __launch_bounds__(256) void ctc_alpha2_kernel(
    const float* __restrict__ logits, const float* __restrict__ denom,
    const int* __restrict__ targets, const int* __restrict__ input_lengths,
    const int* __restrict__ target_lengths, float* __restrict__ per_sample,
    int B, int T, int L)
{
    const int wave = (int)((blockIdx.x * blockDim.x + threadIdx.x) >> 6);
    const int lane = threadIdx.x & 63;
    if (wave >= B) return;
    const int b = wave;
    const int S = 2 * L + 1;
    const int tlen = target_lengths[b];
    const int ilen = input_lengths[b];
    const int end_idx = 2 * tlen;
    int ext_s = BLANK;
    if (lane < S && (lane & 1)) ext_s = targets[b * L + (lane >> 1)];
    const int ext_sm2 = __shfl_up(ext_s, 2);
    const bool skip_ok = (lane < S) && (lane >= 2) && (ext_s != BLANK) && (ext_s != ext_sm2);
    const bool valid = lane < (2 * tlen + 1);
    const float* lg = logits + (size_t)b * T * CC;
    const float* dn = denom + (size_t)b * T;
    float x_cur = lg[ext_s];
    float d_cur = dn[0];
    float x_nx = (T > 1) ? lg[CC + ext_s] : 0.0f;
    float d_nx = (T > 1) ? dn[1] : 0.0f;
    float final_v = NEG;
    float alpha = (valid && lane <= 1) ? (x_cur - d_cur) : NEG;
    if (ilen == 1) {
        const float e1 = __shfl(alpha, end_idx);
        const float e2 = __shfl(alpha, end_idx - 1);
        final_v = logaddexp_f(e1, e2);
    }
    for (int tt = 1; tt < T; ++tt) {
        x_cur = x_nx; d_cur = d_nx;
        if (tt + 1 < T) {
            x_nx = lg[(size_t)(tt + 1) * CC + ext_s];
            d_nx = dn[tt + 1];
        }
        const float lpe = x_cur - d_cur;
        float a1 = __shfl_up(alpha, 1);
        if (lane == 0) a1 = NEG;
        float a2 = __shfl_up(alpha, 2);
        if (!skip_ok) a2 = NEG;
        const float m = fmaxf(fmaxf(alpha, a1), a2);
        const float s = __expf(alpha - m) + __expf(a1 - m) + __expf(a2 - m);
        const float na = m + __logf(s) + lpe;
        alpha = valid ? na : NEG;
        if (ilen == tt + 1) {
            const float e1 = __shfl(alpha, end_idx);
            const float e2 = __shfl(alpha, end_idx - 1);
            final_v = logaddexp_f(e1, e2);
        }
    }
    if (lane == 0) per_sample[b] = -final_v / (float)tlen;
}

__global__ __launch_bounds__(256) void ctc_alpha_mono_kernel(
    const float* __restrict__ logits, const int* __restrict__ targets,
    const int* __restrict__ input_lengths, const int* __restrict__ target_lengths,
    float* __restrict__ per_sample, int B, int T, int L)
{
    const int wave = (int)((blockIdx.x * blockDim.x + threadIdx.x) >> 6);
    const int lane = threadIdx.x & 63;
    if (wave >= B) return;
    const int b = wave;
    const int S = 2 * L + 1;
    const int tlen = target_lengths[b];
    const int ilen = input_lengths[b];
    const int end_idx = 2 * tlen;
    int ext_s = BLANK;
    if (lane < S && (lane & 1)) ext_s = targets[b * L + (lane >> 1)];
    const int ext_sm2 = __shfl_up(ext_s, 2);
    const bool skip_ok = (lane < S) && (lane >= 2) && (ext_s != BLANK) && (ext_s != ext_sm2);
    const bool valid = lane < (2 * tlen + 1);
    const float* lg = logits + (size_t)b * T * CC;
    float alpha = NEG, final_v = NEG;
    for (int t = 0; t < T; ++t) {
        float x = (lane < CC) ? lg[t * CC + lane] : -3.0e38f;
        float mx = x;
        #pragma unroll
        for (int o = 32; o > 0; o >>= 1) mx = fmaxf(mx, __shfl_xor(mx, o));
        float e = (lane < CC) ? __expf(x - mx) : 0.0f;
        float se = e;
        #pragma unroll
        for (int o = 32; o > 0; o >>= 1) se += __shfl_xor(se, o);
        const float lp = x - mx - __logf(se);
        const float lpe = __shfl(lp, ext_s);
        float newa;
        if (t == 0) {
            newa = (lane <= 1) ? lpe : NEG;
        } else {
            float a1 = __shfl_up(alpha, 1);
            if (lane == 0) a1 = NEG;
            float a2 = __shfl_up(alpha, 2);
            if (!skip_ok) a2 = NEG;
            newa = logaddexp_f(logaddexp_f(alpha, a1), a2) + lpe;
        }
        if (!valid) newa = NEG;
        alpha = newa;
        if (ilen == t + 1) {
            const float e1 = __shfl(alpha, end_idx);
            const float e2 = __shfl(alpha, end_idx - 1);
            final_v = logaddexp_f(e1, e2);
        }
    }
    if (lane == 0) per_sample[b] = -final_v / (float)tlen;
}

// ---------------- Deterministic mean over B samples ------------------------
__global__ __launch_bounds__(256) void reduce_mean_kernel(
    const float* __restrict__ ps, float* __restrict__ out, int B)
{
    float s = 0.0f;
    for (int i = threadIdx.x; i < B; i += 256) s += ps[i];
    #pragma unroll
    for (int o = 32; o > 0; o >>= 1) s += __shfl_xor(s, o);
    __shared__ float sm[4];
    const int w = threadIdx.x >> 6, l = threadIdx.x & 63;
    if (l == 0) sm[w] = s;
    __syncthreads();
    if (threadIdx.x == 0) {
        out[0] = (sm[0] + sm[1] + sm[2] + sm[3]) / (float)B;
    }
}

extern "C" void kernel_launch(void* const* d_in, const int* in_sizes, int n_in,
                              void* d_out, int out_size, void* d_ws, size_t ws_size,
                              hipStream_t stream) {
    const float* logits         = (const float*)d_in[0];
    const int*   targets        = (const int*)d_in[1];
    const int*   input_lengths  = (const int*)d_in[2];
    const int*   target_lengths = (const int*)d_in[3];

    const int B = in_sizes[2];
    const int L = in_sizes[1] / B;
    const int T = in_sizes[0] / (B * CC);
    const long long N = (long long)B * T;

    float* per_sample = (float*)d_ws;
    float* scratch    = per_sample + B;
    float* out        = (float*)d_out;

    const size_t ws_mid = ((size_t)B + (size_t)N) * sizeof(float);
    const int nblocks_alpha = (B * 64 + 255) / 256;
    const long long nwaves = (N + 63) / 64;

    const bool ws_ok = ws_size >= (size_t)B * sizeof(float);
    const bool fast2 = (B % 2 == 0) && (T % 64 == 0) && T >= 64 && L <= 16 && ws_ok;
    const bool fast1 = (T % 128 == 0) && T >= 128 && L <= 31 && ws_ok;

    if (fast2) {
        ctc_fused_ab2_kernel<<<B / 2, 128, 0, stream>>>(
            logits, targets, input_lengths, target_lengths, per_sample, B, T, L);
        reduce_mean_kernel<<<1, 256, 0, stream>>>(per_sample, out, B);
    } else if (fast1) {
        ctc_fused_ab_kernel<<<B, 128, 0, stream>>>(
            logits, targets, input_lengths, target_lengths, per_sample, B, T, L);
        reduce_mean_kernel<<<1, 256, 0, stream>>>(per_sample, out, B);
    } else if (ws_size >= ws_mid && T >= 2) {
        lse_kernel<<<(int)((nwaves + 3) / 4), 256, 0, stream>>>(logits, scratch, (int)N);
        ctc_alpha2_kernel<<<nblocks_alpha, 256, 0, stream>>>(
            logits, scratch, targets, input_lengths, target_lengths, per_sample, B, T, L);
        reduce_mean_kernel<<<1, 256, 0, stream>>>(per_sample, out, B);
    } else {
        ctc_alpha_mono_kernel<<<nblocks_alpha, 256, 0, stream>>>(
            logits, targets, input_lengths, target_lengths, per_sample, B, T, L);
        reduce_mean_kernel<<<1, 256, 0, stream>>>(per_sample, out, B);
    }
}